// Round 3
// 2584.650 us; speedup vs baseline: 1.7142x; 1.7142x over previous
//
#include <hip/hip_runtime.h>
#include <hip/hip_bf16.h>
#include <math.h>

// ---------------------------------------------------------------------------
// MHGAT forward on MI355X (gfx950). Inputs/adj are float32 (auto-detected vs
// bf16 by probe_k); weights normalized into a bf16 params block; OUTPUT IS
// FLOAT32 [2048,4] (reference dtype).
// Workspace (MiB offsets), PEAK ~186 MiB:
//  flag@0 | pb bf16 params @64KiB (1.3MB) | dinv@2 | xwb@3(49)
//  h1r@52(49, ALIASES h2 start: h1r dead before h2 written) | h2 f32@52(98)
//  CSR (Phase G only, dead before Phase M): cnt@150 rowptr@151 cursor@152
//    csr_src@153(4) bsum/bofs@158
//  Phase M: seqb@3(15) qb@18 kb@33 vb@150 aob@165 seqo=qb | x0b@180(3) X1b@183(3)
//  Phase A: Hb@52(6) esrc@58 edst@59 msgs@60(36) hx@96(6) msg5@102(6)
// ---------------------------------------------------------------------------

typedef unsigned short u16;
typedef unsigned int   u32;
typedef __attribute__((ext_vector_type(8))) short short8;   // 8 x bf16
typedef __attribute__((ext_vector_type(4))) float f32x4;

#define NNODE 200000
#define NEDGE 1000000
#define NTT   2048

static constexpr size_t MiB = 1024ull * 1024ull;

// params block element offsets (bf16)
enum : unsigned {
    O_W1 = 0,         O_b1 = 32768,     O_W2 = 32896,     O_b2 = 65664,
    O_mhaW = 65792,   O_mhab = 196864,  O_attWq = 197888, O_attWk = 263424,
    O_attv = 328960,  O_fuseW = 329472, O_fuseb = 330496, O_gatW = 330504,
    O_asrc = 428808,  O_adst = 433416,  O_taW = 438024,   O_tab = 634632,
    O_taq = 636168,   O_gc2W = 637704,  O_gc2b = 654088,  O_finW = 654216,
    O_finb = 654728
};

__device__ __forceinline__ float b2f(u16 u) { return __uint_as_float(((u32)u) << 16); }
__device__ __forceinline__ u16 f2b(float f) {
    u32 u = __float_as_uint(f);
    u32 r = (u + 0x7fffu + ((u >> 16) & 1u)) >> 16;   // RNE
    return (u16)r;
}

__device__ __forceinline__ float wsum(float v) {
#pragma unroll
    for (int m = 1; m < 64; m <<= 1) v += __shfl_xor(v, m, 64);
    return v;
}
__device__ __forceinline__ float bsum128(float v, float* s) {
    v = wsum(v);
    __syncthreads();
    if ((threadIdx.x & 63) == 0) s[threadIdx.x >> 6] = v;
    __syncthreads();
    return s[0] + s[1];
}
__device__ __forceinline__ float bmax128(float v, float* s) {
#pragma unroll
    for (int m = 1; m < 64; m <<= 1) v = fmaxf(v, __shfl_xor(v, m, 64));
    __syncthreads();
    if ((threadIdx.x & 63) == 0) s[threadIdx.x >> 6] = v;
    __syncthreads();
    return fmaxf(s[0], s[1]);
}

// ------------------------ dtype probe + param convert ----------------------
// If x is f32, even u16 halves are random mantissa bits (~10% in [1e-6,100]);
// if bf16, they are real N(0,1) values (~100%). flag=1 => f32 inputs.
__global__ __launch_bounds__(256) void probe_k(const void* xsrc, int* flag) {
    __shared__ int cnt;
    if (threadIdx.x == 0) cnt = 0;
    __syncthreads();
    int c = 0;
    for (int i = threadIdx.x; i < 4096; i += 256) {
        float v = fabsf(b2f(((const u16*)xsrc)[2 * i]));
        if (v > 1e-6f && v < 100.f) c++;
    }
    atomicAdd(&cnt, c);
    __syncthreads();
    if (threadIdx.x == 0) flag[0] = (cnt < 2048) ? 1 : 0;
}

struct CEnt { const void* src; unsigned dstOff; unsigned cnt; };
struct CTab { CEnt e[21]; };
__global__ __launch_bounds__(256) void convp_k(CTab tb, u16* pb, const int* flag) {
    bool f32 = flag[0] != 0;
    int stride = gridDim.x * blockDim.x;
    int tid = blockIdx.x * blockDim.x + threadIdx.x;
    for (int k = 0; k < 21; k++) {
        const void* s = tb.e[k].src;
        unsigned off = tb.e[k].dstOff, n = tb.e[k].cnt;
        for (unsigned i = tid; i < n; i += stride)
            pb[off + i] = f32 ? f2b(((const float*)s)[i]) : ((const u16*)s)[i];
    }
}

// ---------------------------------------------------------------------------
// bf16 GEMM: C[M,128] = A[M,K] @ W[K,128] (+bias). MFMA 16x16x32.
// A may be raw input (dtype per flagp) or internal bf16 (flagp=nullptr).
// ---------------------------------------------------------------------------
template <int K, bool OBF>
__global__ __launch_bounds__(256) void gemm_bf16(const void* __restrict__ A,
                                                 const u16* __restrict__ W,
                                                 const u16* __restrict__ bias,
                                                 void* __restrict__ Cv, int M,
                                                 const int* flagp) {
    constexpr int LW = 40;
    __shared__ u16 Al[128 * LW];
    __shared__ u16 Bl[128 * LW];   // W transposed: Bl[n*LW + k]
    const int tid = threadIdx.x;
    const int lane = tid & 63, wv = tid >> 6;
    const int row0 = blockIdx.x * 128;
    const int m16 = lane & 15, oct = lane >> 4;
    const bool aF32 = flagp && (flagp[0] != 0);

    f32x4 acc[2][8];
#pragma unroll
    for (int s = 0; s < 2; s++)
#pragma unroll
        for (int t = 0; t < 8; t++) acc[s][t] = (f32x4){0.f, 0.f, 0.f, 0.f};

    const int r = tid >> 1, kk16 = (tid & 1) * 16;
    const int gr = row0 + r;
    const bool rowOk = (gr < M);

    for (int k0 = 0; k0 < K; k0 += 32) {
        {
            uint4 d0 = {0, 0, 0, 0}, d1 = {0, 0, 0, 0};
            if (rowOk) {
                if (aF32) {
                    const float* src = (const float*)A + (size_t)gr * K + k0 + kk16;
                    union { uint4 v[2]; u16 u[16]; } t;
#pragma unroll
                    for (int q = 0; q < 16; q++) t.u[q] = f2b(src[q]);
                    d0 = t.v[0];
                    d1 = t.v[1];
                } else {
                    const uint4* src = (const uint4*)((const u16*)A + (size_t)gr * K + k0 + kk16);
                    d0 = src[0];
                    d1 = src[1];
                }
            }
            *(uint4*)&Al[r * LW + kk16] = d0;
            *(uint4*)&Al[r * LW + kk16 + 8] = d1;
        }
#pragma unroll
        for (int ii = 0; ii < 16; ii++) {
            int e = tid + ii * 256;       // 0..4095
            int kk = e & 31, n = e >> 5;
            Bl[n * LW + kk] = W[(size_t)(k0 + kk) * 128 + n];
        }
        __syncthreads();

        short8 af0 = *(const short8*)&Al[(wv * 32 + m16) * LW + oct * 8];
        short8 af1 = *(const short8*)&Al[(wv * 32 + 16 + m16) * LW + oct * 8];
        short8 bf[8];
#pragma unroll
        for (int t = 0; t < 8; t++)
            bf[t] = *(const short8*)&Bl[(t * 16 + m16) * LW + oct * 8];
#pragma unroll
        for (int t = 0; t < 8; t++) {
            acc[0][t] = __builtin_amdgcn_mfma_f32_16x16x32_bf16(af0, bf[t], acc[0][t], 0, 0, 0);
            acc[1][t] = __builtin_amdgcn_mfma_f32_16x16x32_bf16(af1, bf[t], acc[1][t], 0, 0, 0);
        }
        __syncthreads();
    }

    float bv[8];
#pragma unroll
    for (int t = 0; t < 8; t++) bv[t] = bias ? b2f(bias[t * 16 + m16]) : 0.f;
#pragma unroll
    for (int s = 0; s < 2; s++)
#pragma unroll
        for (int t = 0; t < 8; t++)
#pragma unroll
            for (int rr = 0; rr < 4; rr++) {
                int orow = row0 + wv * 32 + s * 16 + oct * 4 + rr;
                if (orow < M) {
                    float val = acc[s][t][rr] + bv[t];
                    size_t idx = (size_t)orow * 128 + t * 16 + m16;
                    if (OBF) ((u16*)Cv)[idx] = f2b(val);
                    else     ((float*)Cv)[idx] = val;
                }
            }
}

// conv2 GEMM: A row i = concat(h1r[i], h1r[root(i)]) staged on the fly. K=256.
__global__ __launch_bounds__(256) void gemm_conv2(const u16* __restrict__ h1r,
                                                  const int* __restrict__ batch,
                                                  const int* __restrict__ rootindex,
                                                  const u16* __restrict__ W,
                                                  u16* __restrict__ C, int M) {
    constexpr int LW = 40;
    __shared__ u16 Al[128 * LW];
    __shared__ u16 Bl[128 * LW];
    const int tid = threadIdx.x;
    const int lane = tid & 63, wv = tid >> 6;
    const int row0 = blockIdx.x * 128;
    const int m16 = lane & 15, oct = lane >> 4;

    f32x4 acc[2][8];
#pragma unroll
    for (int s = 0; s < 2; s++)
#pragma unroll
        for (int t = 0; t < 8; t++) acc[s][t] = (f32x4){0.f, 0.f, 0.f, 0.f};

    const int r = tid >> 1, kk16 = (tid & 1) * 16;
    const int gr = row0 + r;
    const u16* pSelf = nullptr; const u16* pRoot = nullptr;
    if (gr < M) {
        pSelf = h1r + (size_t)gr * 128;
        pRoot = h1r + (size_t)rootindex[batch[gr]] * 128;
    }

    for (int k0 = 0; k0 < 256; k0 += 32) {
        {
            int kg = k0 + kk16;   // chunk never straddles the 128 boundary
            uint4 d0 = {0, 0, 0, 0}, d1 = {0, 0, 0, 0};
            if (pSelf) {
                const u16* sp = (kg < 128) ? (pSelf + kg) : (pRoot + kg - 128);
                d0 = ((const uint4*)sp)[0];
                d1 = ((const uint4*)sp)[1];
            }
            *(uint4*)&Al[r * LW + kk16] = d0;
            *(uint4*)&Al[r * LW + kk16 + 8] = d1;
        }
#pragma unroll
        for (int ii = 0; ii < 16; ii++) {
            int e = tid + ii * 256;
            int kk = e & 31, n = e >> 5;
            Bl[n * LW + kk] = W[(size_t)(k0 + kk) * 128 + n];
        }
        __syncthreads();

        short8 af0 = *(const short8*)&Al[(wv * 32 + m16) * LW + oct * 8];
        short8 af1 = *(const short8*)&Al[(wv * 32 + 16 + m16) * LW + oct * 8];
        short8 bf[8];
#pragma unroll
        for (int t = 0; t < 8; t++)
            bf[t] = *(const short8*)&Bl[(t * 16 + m16) * LW + oct * 8];
#pragma unroll
        for (int t = 0; t < 8; t++) {
            acc[0][t] = __builtin_amdgcn_mfma_f32_16x16x32_bf16(af0, bf[t], acc[0][t], 0, 0, 0);
            acc[1][t] = __builtin_amdgcn_mfma_f32_16x16x32_bf16(af1, bf[t], acc[1][t], 0, 0, 0);
        }
        __syncthreads();
    }
#pragma unroll
    for (int s = 0; s < 2; s++)
#pragma unroll
        for (int t = 0; t < 8; t++)
#pragma unroll
            for (int rr = 0; rr < 4; rr++) {
                int orow = row0 + wv * 32 + s * 16 + oct * 4 + rr;
                if (orow < M)
                    C[(size_t)orow * 128 + t * 16 + m16] = f2b(acc[s][t][rr]);
            }
}

// --------------------------- GCN via CSR gather ----------------------------
// Edge list is static across both conv layers: build CSR once (histogram ->
// scan -> fill), then gather per destination node. Zero atomics in the hot
// aggregation; one coalesced write per node; xwb (51 MB) is L3-resident.
__global__ __launch_bounds__(256) void hist_k(const int* __restrict__ ei,
                                              int* __restrict__ cnt) {
    int e = blockIdx.x * 256 + threadIdx.x;
    if (e < NEDGE) atomicAdd(&cnt[ei[NEDGE + e]], 1);
}
// deg[i] = in-degree + 1 (self loop); dinv = rsqrt(deg)
__global__ __launch_bounds__(256) void dinv_k(const int* __restrict__ cnt,
                                              float* __restrict__ dinv) {
    int i = blockIdx.x * 256 + threadIdx.x;
    if (i < NNODE) dinv[i] = rsqrtf((float)(cnt[i] + 1));
}
// scan1: per-1024-chunk block sums
__global__ __launch_bounds__(256) void scan1_k(const int* __restrict__ cnt,
                                               int* __restrict__ bsum) {
    int t = threadIdx.x;
    int base = blockIdx.x * 1024 + t * 4;
    int s = 0;
#pragma unroll
    for (int q = 0; q < 4; q++) {
        int i = base + q;
        if (i < NNODE) s += cnt[i];
    }
#pragma unroll
    for (int m = 1; m < 64; m <<= 1) s += __shfl_xor(s, m, 64);
    __shared__ int ws_[4];
    if ((t & 63) == 0) ws_[t >> 6] = s;
    __syncthreads();
    if (t == 0) bsum[blockIdx.x] = ws_[0] + ws_[1] + ws_[2] + ws_[3];
}
// scan2: serial exclusive scan of ~196 block sums (trivial)
__global__ __launch_bounds__(64) void scan2_k(const int* __restrict__ bsum,
                                              int* __restrict__ bofs, int nb,
                                              int* __restrict__ rowptrN) {
    if (threadIdx.x == 0) {
        int r = 0;
        for (int i = 0; i < nb; i++) { int v = bsum[i]; bofs[i] = r; r += v; }
        *rowptrN = r;
    }
}
// scan3: exclusive scan within each 1024-chunk + block offset -> rowptr,cursor
__global__ __launch_bounds__(256) void scan3_k(const int* __restrict__ cnt,
                                               const int* __restrict__ bofs,
                                               int* __restrict__ rowptr,
                                               int* __restrict__ cursor) {
    int t = threadIdx.x, lane = t & 63, wv = t >> 6;
    int base = blockIdx.x * 1024 + t * 4;
    int v[4];
    int s = 0;
#pragma unroll
    for (int q = 0; q < 4; q++) {
        int i = base + q;
        v[q] = (i < NNODE) ? cnt[i] : 0;
        s += v[q];
    }
    int inc = s;
#pragma unroll
    for (int d = 1; d < 64; d <<= 1) {
        int u = __shfl_up(inc, d, 64);
        if (lane >= d) inc += u;
    }
    __shared__ int wsum_[4];
    if (lane == 63) wsum_[wv] = inc;
    __syncthreads();
    int wofs = 0;
    for (int w = 0; w < wv; w++) wofs += wsum_[w];
    int ex = bofs[blockIdx.x] + wofs + inc - s;
#pragma unroll
    for (int q = 0; q < 4; q++) {
        int i = base + q;
        if (i < NNODE) { rowptr[i] = ex; cursor[i] = ex; }
        ex += v[q];
    }
}
__global__ __launch_bounds__(256) void fill_k(const int* __restrict__ ei,
                                              int* __restrict__ cursor,
                                              int* __restrict__ csr_src) {
    int e = blockIdx.x * 256 + threadIdx.x;
    if (e < NEDGE) {
        int col = ei[NEDGE + e];
        int pos = atomicAdd(&cursor[col], 1);
        csr_src[pos] = ei[e];
    }
}
// one wave per node: gather in-edges, f32 accumulate, fused bias+relu.
// OBF=true -> bf16 output (conv1/h1r); false -> f32 output (conv2/h2).
template <bool OBF>
__global__ __launch_bounds__(256) void gather_gcn_k(const u16* __restrict__ xwb,
                                                    const int* __restrict__ rowptr,
                                                    const int* __restrict__ csr_src,
                                                    const float* __restrict__ dinv,
                                                    const u16* __restrict__ bias,
                                                    void* __restrict__ out) {
    int node = blockIdx.x * 4 + (threadIdx.x >> 6);
    if (node >= NNODE) return;
    int lane = threadIdx.x & 63;
    int beg = rowptr[node], end = rowptr[node + 1];
    int cnt = end - beg;
    // defensive clamp: Poisson(5) in-degree never approaches this; bounds the
    // loop even under hypothetical CSR corruption (hangs kill containers).
    if (cnt < 0) cnt = 0;
    if (cnt > 2048) cnt = 2048;
    end = beg + cnt;
    float di = dinv[node];
    u32 pk = *(const u32*)&xwb[(size_t)node * 128 + lane * 2];
    float selfn = di * di;   // self-loop norm
    float a0 = b2f((u16)(pk & 0xffffu)) * selfn;
    float a1 = b2f((u16)(pk >> 16)) * selfn;
    // lane-parallel prefetch of edge indices + norms, then shfl-broadcast
    int myrow = 0; float mynrm = 0.f;
    if (lane < cnt) {
        myrow = csr_src[beg + lane];
        mynrm = dinv[myrow] * di;
    }
    int n0 = cnt < 64 ? cnt : 64;
    for (int j = 0; j < n0; j++) {
        int row = __shfl(myrow, j, 64);
        float nrm = __shfl(mynrm, j, 64);
        u32 p2 = *(const u32*)&xwb[(size_t)row * 128 + lane * 2];
        a0 += b2f((u16)(p2 & 0xffffu)) * nrm;
        a1 += b2f((u16)(p2 >> 16)) * nrm;
    }
    for (int j = beg + 64; j < end; j++) {   // rare deg>64 tail
        int row = csr_src[j];
        float nrm = dinv[row] * di;
        u32 p2 = *(const u32*)&xwb[(size_t)row * 128 + lane * 2];
        a0 += b2f((u16)(p2 & 0xffffu)) * nrm;
        a1 += b2f((u16)(p2 >> 16)) * nrm;
    }
    a0 = fmaxf(a0 + b2f(bias[lane * 2]), 0.f);
    a1 = fmaxf(a1 + b2f(bias[lane * 2 + 1]), 0.f);
    if (OBF) {
        u32 w = (u32)f2b(a0) | ((u32)f2b(a1) << 16);
        *(u32*)&((u16*)out)[(size_t)node * 128 + lane * 2] = w;
    } else {
        float* op = (float*)out + (size_t)node * 128 + lane * 2;
        op[0] = a0;
        op[1] = a1;
    }
}

// ------------------------- NT-side kernels ---------------------------------
__global__ __launch_bounds__(256) void x0copy_k(const float* h2, const int* tx, u16* x0) {
    int idx = blockIdx.x * 256 + threadIdx.x;   // NTT*128 total
    int n = idx >> 7, c = idx & 127;
    u16 v = f2b(h2[(size_t)tx[n] * 128 + c]);
    x0[idx] = v;
    x0[5 * NTT * 128 + idx] = v;
}
__global__ __launch_bounds__(256) void gather_seq_k(const float* h2, const int* tx,
                                                    u16* seqb, int total) {
    int idx = blockIdx.x * 256 + threadIdx.x;
    if (idx >= total) return;
    int node = tx[idx >> 7];
    seqb[idx] = f2b(h2[(size_t)node * 128 + (idx & 127)]);
}
__global__ __launch_bounds__(128) void addatt12_k(const float* __restrict__ h2,
                                                  const int* tx, const int* rid, const int* pid,
                                                  const u16* __restrict__ Wq,
                                                  const u16* __restrict__ Wk,
                                                  const u16* __restrict__ vv,
                                                  const u16* __restrict__ fw,
                                                  const u16* fbp, int fbi,
                                                  u16* __restrict__ out) {
    int n = blockIdx.x, c = threadIdx.x;
    __shared__ float ls[128], pr[128], rt[128], red[2];
    ls[c] = h2[(size_t)tx[n] * 128 + c];
    pr[c] = h2[(size_t)pid[n] * 128 + c];
    rt[c] = h2[(size_t)rid[n] * 128 + c];
    __syncthreads();
    float qc = 0.f;
    for (int k = 0; k < 128; k++) qc += ls[k] * b2f(Wq[k * 128 + c]);
    float vc = b2f(vv[c]);
    float u0 = qc, u1 = qc;
    for (int k = 0; k < 128; k++) {
        float wk = b2f(Wk[k * 128 + c]);
        u0 += pr[k] * wk;
        u1 += rt[k] * wk;
    }
    float s0 = bsum128(tanhf(u0) * vc, red);
    float s1 = bsum128(tanhf(u1) * vc, red);
    float mx = fmaxf(s0, s1);
    float e0 = expf(s0 - mx), e1 = expf(s1 - mx);
    float iz = 1.f / (e0 + e1);
    float att = (e0 * pr[c] + e1 * rt[c]) * iz;
    float pa = ls[c] * b2f(fw[c]) + att * b2f(fw[128 + c]);
    float alpha = 1.f / (1.f + expf(-(bsum128(pa, red) + b2f(fbp[fbi]))));
    out[(size_t)n * 128 + c] = f2b(alpha * ls[c] + (1.f - alpha) * att);
}
__global__ __launch_bounds__(64) void mha_attn_k(const u16* __restrict__ q,
                                                 const u16* __restrict__ k,
                                                 const u16* __restrict__ v,
                                                 u16* __restrict__ ao, int L) {
    int n = blockIdx.x, h = blockIdx.y, t = threadIdx.x;
    __shared__ float qs[30][16], ks[30][16], vs[30][16], sc[30][30];
    for (int e = t; e < L * 16; e += 64) {
        int l = e >> 4, d = e & 15;
        size_t base = ((size_t)n * L + l) * 128 + h * 16 + d;
        qs[l][d] = b2f(q[base]);
        ks[l][d] = b2f(k[base]);
        vs[l][d] = b2f(v[base]);
    }
    __syncthreads();
    for (int e = t; e < L * L; e += 64) {
        int l = e / L, m = e % L;
        float s = 0.f;
#pragma unroll
        for (int d = 0; d < 16; d++) s += qs[l][d] * ks[m][d];
        sc[l][m] = s * 0.25f;   // 1/sqrt(16)
    }
    __syncthreads();
    if (t < L) {
        float mx = -3e38f;
        for (int m = 0; m < L; m++) mx = fmaxf(mx, sc[t][m]);
        float z = 0.f;
        for (int m = 0; m < L; m++) { float w = expf(sc[t][m] - mx); sc[t][m] = w; z += w; }
        float izz = 1.f / z;
        for (int m = 0; m < L; m++) sc[t][m] *= izz;
    }
    __syncthreads();
    for (int e = t; e < L * 16; e += 64) {
        int l = e >> 4, d = e & 15;
        float o = 0.f;
        for (int m = 0; m < L; m++) o += sc[l][m] * vs[m][d];
        ao[((size_t)n * L + l) * 128 + h * 16 + d] = f2b(o);
    }
}
__global__ __launch_bounds__(128) void addatt_root_k(const u16* __restrict__ seqo,
                                                     const float* __restrict__ h2,
                                                     const int* rid,
                                                     const u16* __restrict__ Wq,
                                                     const u16* __restrict__ Wk,
                                                     const u16* __restrict__ vv,
                                                     const u16* __restrict__ fw,
                                                     const u16* fbp, int fbi, int L,
                                                     u16* __restrict__ out) {
    int n = blockIdx.x, c = threadIdx.x;
    __shared__ float rt[128], srow[128], sl[32], red[2];
    rt[c] = h2[(size_t)rid[n] * 128 + c];
    __syncthreads();
    float qc = 0.f;
    for (int k = 0; k < 128; k++) qc += rt[k] * b2f(Wq[k * 128 + c]);
    float vc = b2f(vv[c]);
    for (int l = 0; l < L; l++) {
        __syncthreads();
        srow[c] = b2f(seqo[((size_t)n * L + l) * 128 + c]);
        __syncthreads();
        float u = qc;
        for (int k = 0; k < 128; k++) u += srow[k] * b2f(Wk[k * 128 + c]);
        float s = bsum128(tanhf(u) * vc, red);
        if (c == 0) sl[l] = s;
    }
    __syncthreads();
    float mx = -3e38f;
    for (int l = 0; l < L; l++) mx = fmaxf(mx, sl[l]);
    float z = 0.f;
    for (int l = 0; l < L; l++) z += expf(sl[l] - mx);
    float att = 0.f;
    for (int l = 0; l < L; l++)
        att += expf(sl[l] - mx) * b2f(seqo[((size_t)n * L + l) * 128 + c]);
    att /= z;
    float pa = rt[c] * b2f(fw[c]) + att * b2f(fw[128 + c]);
    float alpha = 1.f / (1.f + expf(-(bsum128(pa, red) + b2f(fbp[fbi]))));
    out[(size_t)n * 128 + c] = f2b(alpha * rt[c] + (1.f - alpha) * att);
}
__global__ __launch_bounds__(128) void gat_e_k(const float* __restrict__ H,
                                               const u16* __restrict__ asrc,
                                               const u16* __restrict__ adst,
                                               float* esrc, float* edst) {
    int p = blockIdx.y, t1 = p / 6, t2 = p % 6;
    int i = blockIdx.x * 128 + threadIdx.x;
    __shared__ float vs[128], vd[128];
    vs[threadIdx.x] = b2f(asrc[p * 128 + threadIdx.x]);
    vd[threadIdx.x] = b2f(adst[p * 128 + threadIdx.x]);
    __syncthreads();
    const float* r1 = H + ((size_t)t1 * NTT + i) * 128;
    const float* r2 = H + ((size_t)t2 * NTT + i) * 128;
    float s1 = 0.f, s2 = 0.f;
    for (int k = 0; k < 128; k++) { s1 += r1[k] * vs[k]; s2 += r2[k] * vd[k]; }
    esrc[p * NTT + i] = s1;
    edst[p * NTT + i] = s2;
}
// sparse masked-softmax row aggregation; adj dtype per flag
__global__ __launch_bounds__(128) void gc1_attn_k(const void* __restrict__ adjv,
                                                  const float* __restrict__ H,
                                                  const float* __restrict__ esrc,
                                                  const float* __restrict__ edst,
                                                  float* __restrict__ msgs,
                                                  const int* flagp) {
    int i = blockIdx.x, p = blockIdx.y, t = threadIdx.x;
    int t2 = p % 6;
    const bool f32 = flagp[0] != 0;
    size_t rowoff = ((size_t)p * NTT + i) * NTT;
    const float* edp = edst + p * NTT;
    float es = esrc[p * NTT + i];
    __shared__ int nzj[2048];
    __shared__ float nzs[2048];
    __shared__ int cnt;
    __shared__ float red[2];
    if (t == 0) cnt = 0;
    __syncthreads();
    int j0 = t * 16;
    float av[16];
    if (f32) {
        const float4* af = (const float4*)((const float*)adjv + rowoff + j0);
#pragma unroll
        for (int q = 0; q < 4; q++) {
            float4 d = af[q];
            av[q * 4 + 0] = d.x; av[q * 4 + 1] = d.y;
            av[q * 4 + 2] = d.z; av[q * 4 + 3] = d.w;
        }
    } else {
        const u16* ab = (const u16*)adjv + rowoff + j0;
        union { uint4 v; u16 u[8]; } a0, a1;
        a0.v = *(const uint4*)(ab);
        a1.v = *(const uint4*)(ab + 8);
#pragma unroll
        for (int q = 0; q < 16; q++) av[q] = b2f(q < 8 ? a0.u[q] : a1.u[q - 8]);
    }
    float lmax = -3e38f;
#pragma unroll
    for (int jj = 0; jj < 16; jj++) {
        if (av[jj] > 0.f) {
            int j = j0 + jj;
            float e = es + edp[j];
            float sv = e > 0.f ? e : 0.1f * e;   // leaky_relu, GAMMA=0.1
            lmax = fmaxf(lmax, sv);
            int kk = atomicAdd(&cnt, 1);
            nzj[kk] = j;
            nzs[kk] = sv;
        }
    }
    float mx = bmax128(lmax, red);
    int nnz = cnt;
    float psum = 0.f;
    for (int k = t; k < nnz; k += 128) {
        float w = expf(nzs[k] - mx);
        nzs[k] = w;
        psum += w;
    }
    float Z = bsum128(psum, red);
    const float* Ht = H + (size_t)t2 * NTT * 128;
    float acc = 0.f;
    if (nnz > 0) {
        for (int k = 0; k < nnz; k++) acc += nzs[k] * Ht[(size_t)nzj[k] * 128 + t];
        acc /= Z;
    } else {   // all-masked row -> uniform softmax over -1e9 scores
        for (int j = 0; j < NTT; j++) acc += Ht[(size_t)j * 128 + t];
        acc *= (1.f / 2048.f);
    }
    msgs[((size_t)p * NTT + i) * 128 + t] = acc;
}
__global__ __launch_bounds__(128) void at1_k(const float* __restrict__ msgs,
                                             const u16* __restrict__ taW,
                                             const u16* __restrict__ tab,
                                             const u16* __restrict__ taq,
                                             u16* __restrict__ X1) {
    int n = blockIdx.x, t1 = blockIdx.y, c = threadIdx.x;
    __shared__ float mr[6][128], sv[6], red[2];
    const u16* Wt = taW + (size_t)t1 * 16384;
    float bc = b2f(tab[t1 * 128 + c]), qcv = b2f(taq[t1 * 128 + c]);
    for (int t2 = 0; t2 < 6; t2++)
        mr[t2][c] = msgs[(((size_t)t1 * 6 + t2) * NTT + n) * 128 + c];
    __syncthreads();
    for (int t2 = 0; t2 < 6; t2++) {
        float u = bc;
        for (int k = 0; k < 128; k++) u += mr[t2][k] * b2f(Wt[k * 128 + c]);
        float s = bsum128(tanhf(u) * qcv, red);
        if (c == 0) sv[t2] = s;
    }
    __syncthreads();
    float mx = -3e38f;
    for (int t2 = 0; t2 < 6; t2++) mx = fmaxf(mx, sv[t2]);
    float z = 0.f;
    for (int t2 = 0; t2 < 6; t2++) z += expf(sv[t2] - mx);
    float o = 0.f;
    for (int t2 = 0; t2 < 6; t2++) o += expf(sv[t2] - mx) * mr[t2][c];
    o /= z;
    X1[((size_t)t1 * NTT + n) * 128 + c] = f2b(fmaxf(o, 0.f));
}
// dense hop-2 aggregation: adj dtype per flag
__global__ __launch_bounds__(128) void gc2_agg_k(const void* __restrict__ adjv,
                                                 size_t adjBase,
                                                 const float* __restrict__ hx,
                                                 const u16* __restrict__ bias,
                                                 float* __restrict__ msgs5,
                                                 const int* flagp) {
    int i = blockIdx.x, s = blockIdx.y, t = threadIdx.x;
    const bool f32 = flagp[0] != 0;
    size_t rowoff = adjBase + ((size_t)s * NTT + i) * NTT;
    __shared__ int nzj[2048];
    __shared__ float nzw[2048];
    __shared__ int cnt;
    if (t == 0) cnt = 0;
    __syncthreads();
    int j0 = t * 16;
    float av[16];
    if (f32) {
        const float4* af = (const float4*)((const float*)adjv + rowoff + j0);
#pragma unroll
        for (int q = 0; q < 4; q++) {
            float4 d = af[q];
            av[q * 4 + 0] = d.x; av[q * 4 + 1] = d.y;
            av[q * 4 + 2] = d.z; av[q * 4 + 3] = d.w;
        }
    } else {
        const u16* ab = (const u16*)adjv + rowoff + j0;
        union { uint4 v; u16 u[8]; } a0, a1;
        a0.v = *(const uint4*)(ab);
        a1.v = *(const uint4*)(ab + 8);
#pragma unroll
        for (int q = 0; q < 16; q++) av[q] = b2f(q < 8 ? a0.u[q] : a1.u[q - 8]);
    }
#pragma unroll
    for (int jj = 0; jj < 16; jj++) {
        if (av[jj] != 0.f) {
            int kk = atomicAdd(&cnt, 1);
            nzj[kk] = j0 + jj;
            nzw[kk] = av[jj];
        }
    }
    __syncthreads();
    const float* hxs = hx + (size_t)s * NTT * 128;
    float acc = 0.f;
    int nnz = cnt;
    for (int k = 0; k < nnz; k++) acc += nzw[k] * hxs[(size_t)nzj[k] * 128 + t];
    msgs5[((size_t)s * NTT + i) * 128 + t] = acc + b2f(bias[t]);
}
// at2 (ta index 11) + final linear + log_softmax -> FLOAT32 out [2048,4]
__global__ __launch_bounds__(128) void at2_head_k(const float* __restrict__ msgs5,
                                                  const u16* __restrict__ taW,
                                                  const u16* __restrict__ tab,
                                                  const u16* __restrict__ taq,
                                                  const u16* __restrict__ finW,
                                                  const u16* __restrict__ finb,
                                                  float* __restrict__ out) {
    int n = blockIdx.x, c = threadIdx.x;
    __shared__ float mr[6][128], sv[6], red[2];
    const u16* Wt = taW + (size_t)11 * 16384;
    float bc = b2f(tab[11 * 128 + c]), qcv = b2f(taq[11 * 128 + c]);
    for (int s = 0; s < 6; s++)
        mr[s][c] = msgs5[((size_t)s * NTT + n) * 128 + c];
    __syncthreads();
    for (int s = 0; s < 6; s++) {
        float u = bc;
        for (int k = 0; k < 128; k++) u += mr[s][k] * b2f(Wt[k * 128 + c]);
        float sc = bsum128(tanhf(u) * qcv, red);
        if (c == 0) sv[s] = sc;
    }
    __syncthreads();
    float mx = -3e38f;
    for (int s = 0; s < 6; s++) mx = fmaxf(mx, sv[s]);
    float z = 0.f;
    for (int s = 0; s < 6; s++) z += expf(sv[s] - mx);
    float x2c = 0.f;
    for (int s = 0; s < 6; s++) x2c += expf(sv[s] - mx) * mr[s][c];
    x2c /= z;   // no relu in at2
    float l0 = bsum128(x2c * b2f(finW[c * 4 + 0]), red) + b2f(finb[0]);
    float l1 = bsum128(x2c * b2f(finW[c * 4 + 1]), red) + b2f(finb[1]);
    float l2 = bsum128(x2c * b2f(finW[c * 4 + 2]), red) + b2f(finb[2]);
    float l3 = bsum128(x2c * b2f(finW[c * 4 + 3]), red) + b2f(finb[3]);
    float m4 = fmaxf(fmaxf(l0, l1), fmaxf(l2, l3));
    float ls = logf(expf(l0 - m4) + expf(l1 - m4) + expf(l2 - m4) + expf(l3 - m4)) + m4;
    if (c < 4) {
        float v = (c == 0) ? l0 : (c == 1) ? l1 : (c == 2) ? l2 : l3;
        out[n * 4 + c] = v - ls;   // FLOAT32 output (reference dtype)
    }
}

// ---------------------------------------------------------------------------
extern "C" void kernel_launch(void* const* d_in, const int* in_sizes, int n_in,
                              void* d_out, int out_size, void* d_ws, size_t ws_size,
                              hipStream_t stream) {
    const void* x       = d_in[0];
    const int* ei       = (const int*)d_in[1];
    const int* batch    = (const int*)d_in[2];
    const int* rootidx  = (const int*)d_in[3];
    const int* type_x0  = (const int*)d_in[4];
    const int* type_x1  = (const int*)d_in[5];
    const int* type_x2  = (const int*)d_in[6];
    const int* root1    = (const int*)d_in[7];
    const int* parent1  = (const int*)d_in[8];
    const int* root2    = (const int*)d_in[9];
    const int* parent2  = (const int*)d_in[10];
    const int* type_x3  = (const int*)d_in[11];
    const int* root3    = (const int*)d_in[12];
    const int* type_x4  = (const int*)d_in[13];
    const int* root4    = (const int*)d_in[14];
    const void* adj     = d_in[15];

    char* ws = (char*)d_ws;
    int*   flag = (int*)(ws);
    u16*   pb   = (u16*)  (ws + 64 * 1024);   // bf16 params (1.31 MB)
    float* dinv = (float*)(ws + 2 * MiB);
    u16*   xwb  = (u16*)  (ws + 3 * MiB);     // [N,128] bf16 -> [3, 51.83)
    float* h2   = (float*)(ws + 52 * MiB);    // [N,128] f32 -> [52, 149.66)
    u16*   h1r  = (u16*)  (ws + 52 * MiB);    // ALIASES h2 start; dead before
                                              // h2 is written (gather2)
    // CSR scratch @150+ (Phase G only; dead before Phase M's vb@150)
    int*   cnt_i   = (int*)(ws + 150 * MiB);  // [N] in-degree histogram
    int*   rowptr  = (int*)(ws + 151 * MiB);  // [N+1]
    int*   cursor  = (int*)(ws + 152 * MiB);  // [N]
    int*   csr_src = (int*)(ws + 153 * MiB);  // [E] (4 MB) -> [153, 157)
    int*   bsum    = (int*)(ws + 158 * MiB);  // [196]
    int*   bofs    = (int*)(ws + 158 * MiB + 4096);
    // Phase M aliases
    u16*   seqb = (u16*)  (ws + 3 * MiB);     // [61440,128] bf16
    u16*   qb   = (u16*)  (ws + 18 * MiB);
    u16*   kb   = (u16*)  (ws + 33 * MiB);
    u16*   vb   = (u16*)  (ws + 150 * MiB);
    u16*   aob  = (u16*)  (ws + 165 * MiB);
    u16*   seqo = (u16*)  (ws + 18 * MiB);    // alias qb (dead after mha)
    u16*   x0b  = (u16*)  (ws + 180 * MiB);   // [6,2048,128] bf16
    u16*   X1b  = (u16*)  (ws + 183 * MiB);
    // Phase A aliases (h2 dead)
    float* Hb   = (float*)(ws + 52 * MiB);    // [6,2048,128] f32
    float* esrc = (float*)(ws + 58 * MiB);
    float* edst = (float*)(ws + 59 * MiB);
    float* msgs = (float*)(ws + 60 * MiB);    // [36,2048,128] f32
    float* hx   = (float*)(ws + 96 * MiB);
    float* msg5 = (float*)(ws + 102 * MiB);

    // ------- dtype probe + param normalization -------
    probe_k<<<1, 256, 0, stream>>>(x, flag);
    CTab tb;
    int kk = 0;
    auto add = [&](int i, unsigned off, unsigned n) {
        tb.e[kk].src = d_in[i]; tb.e[kk].dstOff = off; tb.e[kk].cnt = n; kk++;
    };
    add(16, O_W1, 32768);   add(17, O_b1, 128);     add(18, O_W2, 32768);
    add(19, O_b2, 128);     add(20, O_mhaW, 131072);add(21, O_mhab, 1024);
    add(22, O_attWq, 65536);add(23, O_attWk, 65536);add(24, O_attv, 512);
    add(25, O_fuseW, 1024); add(26, O_fuseb, 4);    add(27, O_gatW, 98304);
    add(28, O_asrc, 4608);  add(29, O_adst, 4608);  add(30, O_taW, 196608);
    add(31, O_tab, 1536);   add(32, O_taq, 1536);   add(33, O_gc2W, 16384);
    add(34, O_gc2b, 128);   add(35, O_finW, 512);   add(36, O_finb, 4);
    convp_k<<<256, 256, 0, stream>>>(tb, pb, flag);

    // ---------------- Phase G: CSR build (once) + two GCN layers -----------
    const int NB = (NNODE + 1023) / 1024;   // 196 scan blocks
    hipMemsetAsync(cnt_i, 0, (size_t)NNODE * 4, stream);
    hist_k<<<(NEDGE + 255) / 256, 256, 0, stream>>>(ei, cnt_i);
    dinv_k<<<(NNODE + 255) / 256, 256, 0, stream>>>(cnt_i, dinv);
    scan1_k<<<NB, 256, 0, stream>>>(cnt_i, bsum);
    scan2_k<<<1, 64, 0, stream>>>(bsum, bofs, NB, rowptr + NNODE);
    scan3_k<<<NB, 256, 0, stream>>>(cnt_i, bofs, rowptr, cursor);
    fill_k<<<(NEDGE + 255) / 256, 256, 0, stream>>>(ei, cursor, csr_src);

    gemm_bf16<256, true><<<(NNODE + 127) / 128, 256, 0, stream>>>(x, pb + O_W1, (const u16*)nullptr, xwb, NNODE, flag);
    gather_gcn_k<true><<<(NNODE + 3) / 4, 256, 0, stream>>>(xwb, rowptr, csr_src, dinv, pb + O_b1, h1r);

    gemm_conv2<<<(NNODE + 127) / 128, 256, 0, stream>>>(h1r, batch, rootidx, pb + O_W2, xwb, NNODE);
    gather_gcn_k<false><<<(NNODE + 3) / 4, 256, 0, stream>>>(xwb, rowptr, csr_src, dinv, pb + O_b2, h2);

    // ---------------- Phase M: build x0[0..5] ----------------
    x0copy_k<<<(NTT * 128) / 256, 256, 0, stream>>>(h2, type_x0, x0b);
    addatt12_k<<<NTT, 128, 0, stream>>>(h2, type_x1, root1, parent1,
                                        pb + O_attWq, pb + O_attWk, pb + O_attv,
                                        pb + O_fuseW, pb + O_fuseb, 0,
                                        x0b + 1 * NTT * 128);
    addatt12_k<<<NTT, 128, 0, stream>>>(h2, type_x2, root2, parent2,
                                        pb + O_attWq + 16384, pb + O_attWk + 16384,
                                        pb + O_attv + 128, pb + O_fuseW + 256,
                                        pb + O_fuseb, 1,
                                        x0b + 2 * NTT * 128);
    for (int i = 0; i < 2; i++) {
        int L = i ? 30 : 13;
        const int* tx = i ? type_x4 : type_x3;
        const int* rt = i ? root4 : root3;
        int M = NTT * L;
        gather_seq_k<<<(M * 128 + 255) / 256, 256, 0, stream>>>(h2, tx, seqb, M * 128);
        gemm_bf16<128, true><<<(M + 127) / 128, 256, 0, stream>>>(seqb, pb + O_mhaW + (i * 4 + 0) * 16384,
                                                                  pb + O_mhab + (i * 4 + 0) * 128, qb, M, nullptr);
        gemm_bf16<128, true><<<(M + 127) / 128, 256, 0, stream>>>(seqb, pb + O_mhaW + (i * 4 + 1) * 16384,
                                                                  pb + O_mhab + (i * 4 + 1) * 128, kb, M, nullptr);
        gemm_bf16<128, true><<<(M + 127) / 128, 256, 0, stream>>>(seqb, pb + O_mhaW + (i * 4 + 2) * 16384,
                                                                  pb + O_mhab + (i * 4 + 2) * 128, vb, M, nullptr);
        mha_attn_k<<<dim3(NTT, 8), 64, 0, stream>>>(qb, kb, vb, aob, L);
        gemm_bf16<128, true><<<(M + 127) / 128, 256, 0, stream>>>(aob, pb + O_mhaW + (i * 4 + 3) * 16384,
                                                                  pb + O_mhab + (i * 4 + 3) * 128, seqo, M, nullptr);
        addatt_root_k<<<NTT, 128, 0, stream>>>(seqo, h2, rt,
                                               pb + O_attWq + (2 + i) * 16384,
                                               pb + O_attWk + (2 + i) * 16384,
                                               pb + O_attv + (2 + i) * 128,
                                               pb + O_fuseW + (2 + i) * 256,
                                               pb + O_fuseb, 2 + i, L,
                                               x0b + (3 + i) * NTT * 128);
    }

    // ---------------- Phase A: hetero GAT + heads ----------------
    for (int t = 0; t < 6; t++)
        gemm_bf16<128, false><<<NTT / 128, 256, 0, stream>>>(x0b + (size_t)t * NTT * 128,
                                                             pb + O_gatW + t * 16384, (const u16*)nullptr,
                                                             Hb + (size_t)t * NTT * 128, NTT, nullptr);
    gat_e_k<<<dim3(16, 36), 128, 0, stream>>>(Hb, pb + O_asrc, pb + O_adst, esrc, edst);
    gc1_attn_k<<<dim3(NTT, 36), 128, 0, stream>>>(adj, Hb, esrc, edst, msgs, flag);
    at1_k<<<dim3(NTT, 6), 128, 0, stream>>>(msgs, pb + O_taW, pb + O_tab, pb + O_taq, X1b);
    gemm_bf16<128, false><<<(6 * NTT) / 128, 256, 0, stream>>>(X1b, pb + O_gc2W, (const u16*)nullptr, hx, 6 * NTT, nullptr);
    gc2_agg_k<<<dim3(NTT, 6), 128, 0, stream>>>(adj, (size_t)5 * 6 * NTT * NTT, hx,
                                                pb + O_gc2b, msg5, flag);
    at2_head_k<<<NTT, 128, 0, stream>>>(msg5, pb + O_taW, pb + O_tab, pb + O_taq,
                                        pb + O_finW, pb + O_finb, (float*)d_out);
}

// Round 4
// 2265.850 us; speedup vs baseline: 1.9554x; 1.1407x over previous
//
#include <hip/hip_runtime.h>
#include <hip/hip_bf16.h>
#include <math.h>

// ---------------------------------------------------------------------------
// MHGAT forward on MI355X (gfx950). Inputs/adj are float32 (auto-detected vs
// bf16 by probe_k); weights normalized into a bf16 params block; OUTPUT IS
// FLOAT32 [2048,4] (reference dtype).
// Workspace (MiB offsets), PEAK ~186 MiB:
//  flag@0 | pb bf16 params @64KiB (1.3MB) | dinv@2 | xwb@3(49)
//  h1r@52(49, ALIASES h2 start: h1r dead before h2 written) | h2 f32@52(98)
//  CSR (Phase G only, dead before Phase M): cnt@150 rowptr@151 cursor@152
//    csr_src@153(4) bsum/bofs@158
//  Phase M: seqb@3(15) qb@18 kb@33 vb@150 aob@165 seqo=qb kpre@33 (kb dead)
//           x0b@180(3) X1b@183(3)
//  Phase A: Hb@52(6) esrc@58 edst@59 msgs bf16@60(18) ubuf bf16@78(18)
//           hx@96(6) msg5@102(6)
// ---------------------------------------------------------------------------

typedef unsigned short u16;
typedef unsigned int   u32;
typedef __attribute__((ext_vector_type(8))) short short8;   // 8 x bf16
typedef __attribute__((ext_vector_type(4))) float f32x4;

#define NNODE 200000
#define NEDGE 1000000
#define NTT   2048

static constexpr size_t MiB = 1024ull * 1024ull;

// params block element offsets (bf16)
enum : unsigned {
    O_W1 = 0,         O_b1 = 32768,     O_W2 = 32896,     O_b2 = 65664,
    O_mhaW = 65792,   O_mhab = 196864,  O_attWq = 197888, O_attWk = 263424,
    O_attv = 328960,  O_fuseW = 329472, O_fuseb = 330496, O_gatW = 330504,
    O_asrc = 428808,  O_adst = 433416,  O_taW = 438024,   O_tab = 634632,
    O_taq = 636168,   O_gc2W = 637704,  O_gc2b = 654088,  O_finW = 654216,
    O_finb = 654728
};

__device__ __forceinline__ float b2f(u16 u) { return __uint_as_float(((u32)u) << 16); }
__device__ __forceinline__ u16 f2b(float f) {
    u32 u = __float_as_uint(f);
    u32 r = (u + 0x7fffu + ((u >> 16) & 1u)) >> 16;   // RNE
    return (u16)r;
}

__device__ __forceinline__ float wsum(float v) {
#pragma unroll
    for (int m = 1; m < 64; m <<= 1) v += __shfl_xor(v, m, 64);
    return v;
}
__device__ __forceinline__ float bsum128(float v, float* s) {
    v = wsum(v);
    __syncthreads();
    if ((threadIdx.x & 63) == 0) s[threadIdx.x >> 6] = v;
    __syncthreads();
    return s[0] + s[1];
}
__device__ __forceinline__ float bmax128(float v, float* s) {
#pragma unroll
    for (int m = 1; m < 64; m <<= 1) v = fmaxf(v, __shfl_xor(v, m, 64));
    __syncthreads();
    if ((threadIdx.x & 63) == 0) s[threadIdx.x >> 6] = v;
    __syncthreads();
    return fmaxf(s[0], s[1]);
}

// ------------------------ dtype probe + param convert ----------------------
__global__ __launch_bounds__(256) void probe_k(const void* xsrc, int* flag) {
    __shared__ int cnt;
    if (threadIdx.x == 0) cnt = 0;
    __syncthreads();
    int c = 0;
    for (int i = threadIdx.x; i < 4096; i += 256) {
        float v = fabsf(b2f(((const u16*)xsrc)[2 * i]));
        if (v > 1e-6f && v < 100.f) c++;
    }
    atomicAdd(&cnt, c);
    __syncthreads();
    if (threadIdx.x == 0) flag[0] = (cnt < 2048) ? 1 : 0;
}

struct CEnt { const void* src; unsigned dstOff; unsigned cnt; };
struct CTab { CEnt e[21]; };
__global__ __launch_bounds__(256) void convp_k(CTab tb, u16* pb, const int* flag) {
    bool f32 = flag[0] != 0;
    int stride = gridDim.x * blockDim.x;
    int tid = blockIdx.x * blockDim.x + threadIdx.x;
    for (int k = 0; k < 21; k++) {
        const void* s = tb.e[k].src;
        unsigned off = tb.e[k].dstOff, n = tb.e[k].cnt;
        for (unsigned i = tid; i < n; i += stride)
            pb[off + i] = f32 ? f2b(((const float*)s)[i]) : ((const u16*)s)[i];
    }
}

// ---------------------------------------------------------------------------
// bf16 GEMM: C[M,128] = A[M,K] @ W[K,128] (+bias). MFMA 16x16x32.
// A may be raw input (dtype per flagp) or internal bf16 (flagp=nullptr).
// ---------------------------------------------------------------------------
template <int K, bool OBF>
__global__ __launch_bounds__(256) void gemm_bf16(const void* __restrict__ A,
                                                 const u16* __restrict__ W,
                                                 const u16* __restrict__ bias,
                                                 void* __restrict__ Cv, int M,
                                                 const int* flagp) {
    constexpr int LW = 40;
    __shared__ u16 Al[128 * LW];
    __shared__ u16 Bl[128 * LW];   // W transposed: Bl[n*LW + k]
    const int tid = threadIdx.x;
    const int lane = tid & 63, wv = tid >> 6;
    const int row0 = blockIdx.x * 128;
    const int m16 = lane & 15, oct = lane >> 4;
    const bool aF32 = flagp && (flagp[0] != 0);

    f32x4 acc[2][8];
#pragma unroll
    for (int s = 0; s < 2; s++)
#pragma unroll
        for (int t = 0; t < 8; t++) acc[s][t] = (f32x4){0.f, 0.f, 0.f, 0.f};

    const int r = tid >> 1, kk16 = (tid & 1) * 16;
    const int gr = row0 + r;
    const bool rowOk = (gr < M);

    for (int k0 = 0; k0 < K; k0 += 32) {
        {
            uint4 d0 = {0, 0, 0, 0}, d1 = {0, 0, 0, 0};
            if (rowOk) {
                if (aF32) {
                    const float* src = (const float*)A + (size_t)gr * K + k0 + kk16;
                    union { uint4 v[2]; u16 u[16]; } t;
#pragma unroll
                    for (int q = 0; q < 16; q++) t.u[q] = f2b(src[q]);
                    d0 = t.v[0];
                    d1 = t.v[1];
                } else {
                    const uint4* src = (const uint4*)((const u16*)A + (size_t)gr * K + k0 + kk16);
                    d0 = src[0];
                    d1 = src[1];
                }
            }
            *(uint4*)&Al[r * LW + kk16] = d0;
            *(uint4*)&Al[r * LW + kk16 + 8] = d1;
        }
#pragma unroll
        for (int ii = 0; ii < 16; ii++) {
            int e = tid + ii * 256;       // 0..4095
            int kk = e & 31, n = e >> 5;
            Bl[n * LW + kk] = W[(size_t)(k0 + kk) * 128 + n];
        }
        __syncthreads();

        short8 af0 = *(const short8*)&Al[(wv * 32 + m16) * LW + oct * 8];
        short8 af1 = *(const short8*)&Al[(wv * 32 + 16 + m16) * LW + oct * 8];
        short8 bf[8];
#pragma unroll
        for (int t = 0; t < 8; t++)
            bf[t] = *(const short8*)&Bl[(t * 16 + m16) * LW + oct * 8];
#pragma unroll
        for (int t = 0; t < 8; t++) {
            acc[0][t] = __builtin_amdgcn_mfma_f32_16x16x32_bf16(af0, bf[t], acc[0][t], 0, 0, 0);
            acc[1][t] = __builtin_amdgcn_mfma_f32_16x16x32_bf16(af1, bf[t], acc[1][t], 0, 0, 0);
        }
        __syncthreads();
    }

    float bv[8];
#pragma unroll
    for (int t = 0; t < 8; t++) bv[t] = bias ? b2f(bias[t * 16 + m16]) : 0.f;
#pragma unroll
    for (int s = 0; s < 2; s++)
#pragma unroll
        for (int t = 0; t < 8; t++)
#pragma unroll
            for (int rr = 0; rr < 4; rr++) {
                int orow = row0 + wv * 32 + s * 16 + oct * 4 + rr;
                if (orow < M) {
                    float val = acc[s][t][rr] + bv[t];
                    size_t idx = (size_t)orow * 128 + t * 16 + m16;
                    if (OBF) ((u16*)Cv)[idx] = f2b(val);
                    else     ((float*)Cv)[idx] = val;
                }
            }
}

// Batched variant: blockIdx.y selects slab y with element strides for A/W/
// bias/C. A is always internal bf16. Used for the 6 gat GEMMs (one launch)
// and at1's u = msgs @ taW[t1] + tab[t1] (6 t1 in one launch).
template <int K, bool OBF>
__global__ __launch_bounds__(256) void gemm_bat_k(const u16* __restrict__ A0, size_t Astride,
                                                  const u16* __restrict__ W0, unsigned Wstride,
                                                  const u16* __restrict__ bias0, unsigned bStride,
                                                  void* __restrict__ Cv, size_t Cstride,
                                                  int M) {
    constexpr int LW = 40;
    __shared__ u16 Al[128 * LW];
    __shared__ u16 Bl[128 * LW];
    const int y = blockIdx.y;
    const u16* A = A0 + (size_t)y * Astride;
    const u16* W = W0 + (size_t)y * Wstride;
    const u16* bias = bias0 ? (bias0 + (size_t)y * bStride) : nullptr;
    const size_t cbase = (size_t)y * Cstride;
    const int tid = threadIdx.x;
    const int lane = tid & 63, wv = tid >> 6;
    const int row0 = blockIdx.x * 128;
    const int m16 = lane & 15, oct = lane >> 4;

    f32x4 acc[2][8];
#pragma unroll
    for (int s = 0; s < 2; s++)
#pragma unroll
        for (int t = 0; t < 8; t++) acc[s][t] = (f32x4){0.f, 0.f, 0.f, 0.f};

    const int r = tid >> 1, kk16 = (tid & 1) * 16;
    const int gr = row0 + r;
    const bool rowOk = (gr < M);

    for (int k0 = 0; k0 < K; k0 += 32) {
        {
            uint4 d0 = {0, 0, 0, 0}, d1 = {0, 0, 0, 0};
            if (rowOk) {
                const uint4* src = (const uint4*)(A + (size_t)gr * K + k0 + kk16);
                d0 = src[0];
                d1 = src[1];
            }
            *(uint4*)&Al[r * LW + kk16] = d0;
            *(uint4*)&Al[r * LW + kk16 + 8] = d1;
        }
#pragma unroll
        for (int ii = 0; ii < 16; ii++) {
            int e = tid + ii * 256;
            int kk = e & 31, n = e >> 5;
            Bl[n * LW + kk] = W[(size_t)(k0 + kk) * 128 + n];
        }
        __syncthreads();

        short8 af0 = *(const short8*)&Al[(wv * 32 + m16) * LW + oct * 8];
        short8 af1 = *(const short8*)&Al[(wv * 32 + 16 + m16) * LW + oct * 8];
        short8 bf[8];
#pragma unroll
        for (int t = 0; t < 8; t++)
            bf[t] = *(const short8*)&Bl[(t * 16 + m16) * LW + oct * 8];
#pragma unroll
        for (int t = 0; t < 8; t++) {
            acc[0][t] = __builtin_amdgcn_mfma_f32_16x16x32_bf16(af0, bf[t], acc[0][t], 0, 0, 0);
            acc[1][t] = __builtin_amdgcn_mfma_f32_16x16x32_bf16(af1, bf[t], acc[1][t], 0, 0, 0);
        }
        __syncthreads();
    }

    float bv[8];
#pragma unroll
    for (int t = 0; t < 8; t++) bv[t] = bias ? b2f(bias[t * 16 + m16]) : 0.f;
#pragma unroll
    for (int s = 0; s < 2; s++)
#pragma unroll
        for (int t = 0; t < 8; t++)
#pragma unroll
            for (int rr = 0; rr < 4; rr++) {
                int orow = row0 + wv * 32 + s * 16 + oct * 4 + rr;
                if (orow < M) {
                    float val = acc[s][t][rr] + bv[t];
                    size_t idx = cbase + (size_t)orow * 128 + t * 16 + m16;
                    if (OBF) ((u16*)Cv)[idx] = f2b(val);
                    else     ((float*)Cv)[idx] = val;
                }
            }
}

// conv2 GEMM: A row i = concat(h1r[i], h1r[root(i)]) staged on the fly. K=256.
__global__ __launch_bounds__(256) void gemm_conv2(const u16* __restrict__ h1r,
                                                  const int* __restrict__ batch,
                                                  const int* __restrict__ rootindex,
                                                  const u16* __restrict__ W,
                                                  u16* __restrict__ C, int M) {
    constexpr int LW = 40;
    __shared__ u16 Al[128 * LW];
    __shared__ u16 Bl[128 * LW];
    const int tid = threadIdx.x;
    const int lane = tid & 63, wv = tid >> 6;
    const int row0 = blockIdx.x * 128;
    const int m16 = lane & 15, oct = lane >> 4;

    f32x4 acc[2][8];
#pragma unroll
    for (int s = 0; s < 2; s++)
#pragma unroll
        for (int t = 0; t < 8; t++) acc[s][t] = (f32x4){0.f, 0.f, 0.f, 0.f};

    const int r = tid >> 1, kk16 = (tid & 1) * 16;
    const int gr = row0 + r;
    const u16* pSelf = nullptr; const u16* pRoot = nullptr;
    if (gr < M) {
        pSelf = h1r + (size_t)gr * 128;
        pRoot = h1r + (size_t)rootindex[batch[gr]] * 128;
    }

    for (int k0 = 0; k0 < 256; k0 += 32) {
        {
            int kg = k0 + kk16;   // chunk never straddles the 128 boundary
            uint4 d0 = {0, 0, 0, 0}, d1 = {0, 0, 0, 0};
            if (pSelf) {
                const u16* sp = (kg < 128) ? (pSelf + kg) : (pRoot + kg - 128);
                d0 = ((const uint4*)sp)[0];
                d1 = ((const uint4*)sp)[1];
            }
            *(uint4*)&Al[r * LW + kk16] = d0;
            *(uint4*)&Al[r * LW + kk16 + 8] = d1;
        }
#pragma unroll
        for (int ii = 0; ii < 16; ii++) {
            int e = tid + ii * 256;
            int kk = e & 31, n = e >> 5;
            Bl[n * LW + kk] = W[(size_t)(k0 + kk) * 128 + n];
        }
        __syncthreads();

        short8 af0 = *(const short8*)&Al[(wv * 32 + m16) * LW + oct * 8];
        short8 af1 = *(const short8*)&Al[(wv * 32 + 16 + m16) * LW + oct * 8];
        short8 bf[8];
#pragma unroll
        for (int t = 0; t < 8; t++)
            bf[t] = *(const short8*)&Bl[(t * 16 + m16) * LW + oct * 8];
#pragma unroll
        for (int t = 0; t < 8; t++) {
            acc[0][t] = __builtin_amdgcn_mfma_f32_16x16x32_bf16(af0, bf[t], acc[0][t], 0, 0, 0);
            acc[1][t] = __builtin_amdgcn_mfma_f32_16x16x32_bf16(af1, bf[t], acc[1][t], 0, 0, 0);
        }
        __syncthreads();
    }
#pragma unroll
    for (int s = 0; s < 2; s++)
#pragma unroll
        for (int t = 0; t < 8; t++)
#pragma unroll
            for (int rr = 0; rr < 4; rr++) {
                int orow = row0 + wv * 32 + s * 16 + oct * 4 + rr;
                if (orow < M)
                    C[(size_t)orow * 128 + t * 16 + m16] = f2b(acc[s][t][rr]);
            }
}

// --------------------------- GCN via CSR gather ----------------------------
__global__ __launch_bounds__(256) void hist_k(const int* __restrict__ ei,
                                              int* __restrict__ cnt) {
    int e = blockIdx.x * 256 + threadIdx.x;
    if (e < NEDGE) atomicAdd(&cnt[ei[NEDGE + e]], 1);
}
__global__ __launch_bounds__(256) void dinv_k(const int* __restrict__ cnt,
                                              float* __restrict__ dinv) {
    int i = blockIdx.x * 256 + threadIdx.x;
    if (i < NNODE) dinv[i] = rsqrtf((float)(cnt[i] + 1));
}
__global__ __launch_bounds__(256) void scan1_k(const int* __restrict__ cnt,
                                               int* __restrict__ bsum) {
    int t = threadIdx.x;
    int base = blockIdx.x * 1024 + t * 4;
    int s = 0;
#pragma unroll
    for (int q = 0; q < 4; q++) {
        int i = base + q;
        if (i < NNODE) s += cnt[i];
    }
#pragma unroll
    for (int m = 1; m < 64; m <<= 1) s += __shfl_xor(s, m, 64);
    __shared__ int ws_[4];
    if ((t & 63) == 0) ws_[t >> 6] = s;
    __syncthreads();
    if (t == 0) bsum[blockIdx.x] = ws_[0] + ws_[1] + ws_[2] + ws_[3];
}
__global__ __launch_bounds__(64) void scan2_k(const int* __restrict__ bsum,
                                              int* __restrict__ bofs, int nb,
                                              int* __restrict__ rowptrN) {
    if (threadIdx.x == 0) {
        int r = 0;
        for (int i = 0; i < nb; i++) { int v = bsum[i]; bofs[i] = r; r += v; }
        *rowptrN = r;
    }
}
__global__ __launch_bounds__(256) void scan3_k(const int* __restrict__ cnt,
                                               const int* __restrict__ bofs,
                                               int* __restrict__ rowptr,
                                               int* __restrict__ cursor) {
    int t = threadIdx.x, lane = t & 63, wv = t >> 6;
    int base = blockIdx.x * 1024 + t * 4;
    int v[4];
    int s = 0;
#pragma unroll
    for (int q = 0; q < 4; q++) {
        int i = base + q;
        v[q] = (i < NNODE) ? cnt[i] : 0;
        s += v[q];
    }
    int inc = s;
#pragma unroll
    for (int d = 1; d < 64; d <<= 1) {
        int u = __shfl_up(inc, d, 64);
        if (lane >= d) inc += u;
    }
    __shared__ int wsum_[4];
    if (lane == 63) wsum_[wv] = inc;
    __syncthreads();
    int wofs = 0;
    for (int w = 0; w < wv; w++) wofs += wsum_[w];
    int ex = bofs[blockIdx.x] + wofs + inc - s;
#pragma unroll
    for (int q = 0; q < 4; q++) {
        int i = base + q;
        if (i < NNODE) { rowptr[i] = ex; cursor[i] = ex; }
        ex += v[q];
    }
}
__global__ __launch_bounds__(256) void fill_k(const int* __restrict__ ei,
                                              int* __restrict__ cursor,
                                              int* __restrict__ csr_src) {
    int e = blockIdx.x * 256 + threadIdx.x;
    if (e < NEDGE) {
        int col = ei[NEDGE + e];
        int pos = atomicAdd(&cursor[col], 1);
        csr_src[pos] = ei[e];
    }
}
// one wave per node: gather in-edges, f32 accumulate, fused bias+relu.
template <bool OBF>
__global__ __launch_bounds__(256) void gather_gcn_k(const u16* __restrict__ xwb,
                                                    const int* __restrict__ rowptr,
                                                    const int* __restrict__ csr_src,
                                                    const float* __restrict__ dinv,
                                                    const u16* __restrict__ bias,
                                                    void* __restrict__ out) {
    int node = blockIdx.x * 4 + (threadIdx.x >> 6);
    if (node >= NNODE) return;
    int lane = threadIdx.x & 63;
    int beg = rowptr[node], end = rowptr[node + 1];
    int cnt = end - beg;
    if (cnt < 0) cnt = 0;
    if (cnt > 2048) cnt = 2048;
    end = beg + cnt;
    float di = dinv[node];
    u32 pk = *(const u32*)&xwb[(size_t)node * 128 + lane * 2];
    float selfn = di * di;   // self-loop norm
    float a0 = b2f((u16)(pk & 0xffffu)) * selfn;
    float a1 = b2f((u16)(pk >> 16)) * selfn;
    int myrow = 0; float mynrm = 0.f;
    if (lane < cnt) {
        myrow = csr_src[beg + lane];
        mynrm = dinv[myrow] * di;
    }
    int n0 = cnt < 64 ? cnt : 64;
    for (int j = 0; j < n0; j++) {
        int row = __shfl(myrow, j, 64);
        float nrm = __shfl(mynrm, j, 64);
        u32 p2 = *(const u32*)&xwb[(size_t)row * 128 + lane * 2];
        a0 += b2f((u16)(p2 & 0xffffu)) * nrm;
        a1 += b2f((u16)(p2 >> 16)) * nrm;
    }
    for (int j = beg + 64; j < end; j++) {
        int row = csr_src[j];
        float nrm = dinv[row] * di;
        u32 p2 = *(const u32*)&xwb[(size_t)row * 128 + lane * 2];
        a0 += b2f((u16)(p2 & 0xffffu)) * nrm;
        a1 += b2f((u16)(p2 >> 16)) * nrm;
    }
    a0 = fmaxf(a0 + b2f(bias[lane * 2]), 0.f);
    a1 = fmaxf(a1 + b2f(bias[lane * 2 + 1]), 0.f);
    if (OBF) {
        u32 w = (u32)f2b(a0) | ((u32)f2b(a1) << 16);
        *(u32*)&((u16*)out)[(size_t)node * 128 + lane * 2] = w;
    } else {
        float* op = (float*)out + (size_t)node * 128 + lane * 2;
        op[0] = a0;
        op[1] = a1;
    }
}

// ------------------------- NT-side kernels ---------------------------------
__global__ __launch_bounds__(256) void x0copy_k(const float* h2, const int* tx, u16* x0) {
    int idx = blockIdx.x * 256 + threadIdx.x;   // NTT*128 total
    int n = idx >> 7, c = idx & 127;
    u16 v = f2b(h2[(size_t)tx[n] * 128 + c]);
    x0[idx] = v;
    x0[5 * NTT * 128 + idx] = v;
}
__global__ __launch_bounds__(256) void gather_seq_k(const float* h2, const int* tx,
                                                    u16* seqb, int total) {
    int idx = blockIdx.x * 256 + threadIdx.x;
    if (idx >= total) return;
    int node = tx[idx >> 7];
    seqb[idx] = f2b(h2[(size_t)node * 128 + (idx & 127)]);
}
__global__ __launch_bounds__(128) void addatt12_k(const float* __restrict__ h2,
                                                  const int* tx, const int* rid, const int* pid,
                                                  const u16* __restrict__ Wq,
                                                  const u16* __restrict__ Wk,
                                                  const u16* __restrict__ vv,
                                                  const u16* __restrict__ fw,
                                                  const u16* fbp, int fbi,
                                                  u16* __restrict__ out) {
    int n = blockIdx.x, c = threadIdx.x;
    __shared__ float ls[128], pr[128], rt[128], red[2];
    ls[c] = h2[(size_t)tx[n] * 128 + c];
    pr[c] = h2[(size_t)pid[n] * 128 + c];
    rt[c] = h2[(size_t)rid[n] * 128 + c];
    __syncthreads();
    float qc = 0.f;
    for (int k = 0; k < 128; k++) qc += ls[k] * b2f(Wq[k * 128 + c]);
    float vc = b2f(vv[c]);
    float u0 = qc, u1 = qc;
    for (int k = 0; k < 128; k++) {
        float wk = b2f(Wk[k * 128 + c]);
        u0 += pr[k] * wk;
        u1 += rt[k] * wk;
    }
    float s0 = bsum128(tanhf(u0) * vc, red);
    float s1 = bsum128(tanhf(u1) * vc, red);
    float mx = fmaxf(s0, s1);
    float e0 = expf(s0 - mx), e1 = expf(s1 - mx);
    float iz = 1.f / (e0 + e1);
    float att = (e0 * pr[c] + e1 * rt[c]) * iz;
    float pa = ls[c] * b2f(fw[c]) + att * b2f(fw[128 + c]);
    float alpha = 1.f / (1.f + expf(-(bsum128(pa, red) + b2f(fbp[fbi]))));
    out[(size_t)n * 128 + c] = f2b(alpha * ls[c] + (1.f - alpha) * att);
}
__global__ __launch_bounds__(64) void mha_attn_k(const u16* __restrict__ q,
                                                 const u16* __restrict__ k,
                                                 const u16* __restrict__ v,
                                                 u16* __restrict__ ao, int L) {
    int n = blockIdx.x, h = blockIdx.y, t = threadIdx.x;
    __shared__ float qs[30][16], ks[30][16], vs[30][16], sc[30][30];
    for (int e = t; e < L * 16; e += 64) {
        int l = e >> 4, d = e & 15;
        size_t base = ((size_t)n * L + l) * 128 + h * 16 + d;
        qs[l][d] = b2f(q[base]);
        ks[l][d] = b2f(k[base]);
        vs[l][d] = b2f(v[base]);
    }
    __syncthreads();
    for (int e = t; e < L * L; e += 64) {
        int l = e / L, m = e % L;
        float s = 0.f;
#pragma unroll
        for (int d = 0; d < 16; d++) s += qs[l][d] * ks[m][d];
        sc[l][m] = s * 0.25f;   // 1/sqrt(16)
    }
    __syncthreads();
    if (t < L) {
        float mx = -3e38f;
        for (int m = 0; m < L; m++) mx = fmaxf(mx, sc[t][m]);
        float z = 0.f;
        for (int m = 0; m < L; m++) { float w = expf(sc[t][m] - mx); sc[t][m] = w; z += w; }
        float izz = 1.f / z;
        for (int m = 0; m < L; m++) sc[t][m] *= izz;
    }
    __syncthreads();
    for (int e = t; e < L * 16; e += 64) {
        int l = e >> 4, d = e & 15;
        float o = 0.f;
        for (int m = 0; m < L; m++) o += sc[l][m] * vs[m][d];
        ao[((size_t)n * L + l) * 128 + h * 16 + d] = f2b(o);
    }
}
// addatt_root with precomputed kpre = seqo @ Wk (GEMM): per-l body is one
// load + tanh + reduce instead of a 128-load dot product.
__global__ __launch_bounds__(128) void addatt_root_k(const u16* __restrict__ seqo,
                                                     const u16* __restrict__ kpre,
                                                     const float* __restrict__ h2,
                                                     const int* rid,
                                                     const u16* __restrict__ Wq,
                                                     const u16* __restrict__ vv,
                                                     const u16* __restrict__ fw,
                                                     const u16* fbp, int fbi, int L,
                                                     u16* __restrict__ out) {
    int n = blockIdx.x, c = threadIdx.x;
    __shared__ float rt[128], sl[32], red[2];
    rt[c] = h2[(size_t)rid[n] * 128 + c];
    __syncthreads();
    float qc = 0.f;
    for (int k = 0; k < 128; k++) qc += rt[k] * b2f(Wq[k * 128 + c]);
    float vc = b2f(vv[c]);
    for (int l = 0; l < L; l++) {
        float u = qc + b2f(kpre[((size_t)n * L + l) * 128 + c]);
        float s = bsum128(tanhf(u) * vc, red);
        if (c == 0) sl[l] = s;
    }
    __syncthreads();
    float mx = -3e38f;
    for (int l = 0; l < L; l++) mx = fmaxf(mx, sl[l]);
    float z = 0.f;
    for (int l = 0; l < L; l++) z += expf(sl[l] - mx);
    float att = 0.f;
    for (int l = 0; l < L; l++)
        att += expf(sl[l] - mx) * b2f(seqo[((size_t)n * L + l) * 128 + c]);
    att /= z;
    float pa = rt[c] * b2f(fw[c]) + att * b2f(fw[128 + c]);
    float alpha = 1.f / (1.f + expf(-(bsum128(pa, red) + b2f(fbp[fbi]))));
    out[(size_t)n * 128 + c] = f2b(alpha * rt[c] + (1.f - alpha) * att);
}
__global__ __launch_bounds__(128) void gat_e_k(const float* __restrict__ H,
                                               const u16* __restrict__ asrc,
                                               const u16* __restrict__ adst,
                                               float* esrc, float* edst) {
    int p = blockIdx.y, t1 = p / 6, t2 = p % 6;
    int i = blockIdx.x * 128 + threadIdx.x;
    __shared__ float vs[128], vd[128];
    vs[threadIdx.x] = b2f(asrc[p * 128 + threadIdx.x]);
    vd[threadIdx.x] = b2f(adst[p * 128 + threadIdx.x]);
    __syncthreads();
    const float* r1 = H + ((size_t)t1 * NTT + i) * 128;
    const float* r2 = H + ((size_t)t2 * NTT + i) * 128;
    float s1 = 0.f, s2 = 0.f;
    for (int k = 0; k < 128; k++) { s1 += r1[k] * vs[k]; s2 += r2[k] * vd[k]; }
    esrc[p * NTT + i] = s1;
    edst[p * NTT + i] = s2;
}
// sparse masked-softmax row aggregation; adj dtype per flag; bf16 output
__global__ __launch_bounds__(128) void gc1_attn_k(const void* __restrict__ adjv,
                                                  const float* __restrict__ H,
                                                  const float* __restrict__ esrc,
                                                  const float* __restrict__ edst,
                                                  u16* __restrict__ msgs,
                                                  const int* flagp) {
    int i = blockIdx.x, p = blockIdx.y, t = threadIdx.x;
    int t2 = p % 6;
    const bool f32 = flagp[0] != 0;
    size_t rowoff = ((size_t)p * NTT + i) * NTT;
    const float* edp = edst + p * NTT;
    float es = esrc[p * NTT + i];
    __shared__ int nzj[2048];
    __shared__ float nzs[2048];
    __shared__ int cnt;
    __shared__ float red[2];
    if (t == 0) cnt = 0;
    __syncthreads();
    int j0 = t * 16;
    float av[16];
    if (f32) {
        const float4* af = (const float4*)((const float*)adjv + rowoff + j0);
#pragma unroll
        for (int q = 0; q < 4; q++) {
            float4 d = af[q];
            av[q * 4 + 0] = d.x; av[q * 4 + 1] = d.y;
            av[q * 4 + 2] = d.z; av[q * 4 + 3] = d.w;
        }
    } else {
        const u16* ab = (const u16*)adjv + rowoff + j0;
        union { uint4 v; u16 u[8]; } a0, a1;
        a0.v = *(const uint4*)(ab);
        a1.v = *(const uint4*)(ab + 8);
#pragma unroll
        for (int q = 0; q < 16; q++) av[q] = b2f(q < 8 ? a0.u[q] : a1.u[q - 8]);
    }
    float lmax = -3e38f;
#pragma unroll
    for (int jj = 0; jj < 16; jj++) {
        if (av[jj] > 0.f) {
            int j = j0 + jj;
            float e = es + edp[j];
            float sv = e > 0.f ? e : 0.1f * e;   // leaky_relu, GAMMA=0.1
            lmax = fmaxf(lmax, sv);
            int kk = atomicAdd(&cnt, 1);
            nzj[kk] = j;
            nzs[kk] = sv;
        }
    }
    float mx = bmax128(lmax, red);
    int nnz = cnt;
    float psum = 0.f;
    for (int k = t; k < nnz; k += 128) {
        float w = expf(nzs[k] - mx);
        nzs[k] = w;
        psum += w;
    }
    float Z = bsum128(psum, red);
    const float* Ht = H + (size_t)t2 * NTT * 128;
    float acc = 0.f;
    if (nnz > 0) {
        for (int k = 0; k < nnz; k++) acc += nzs[k] * Ht[(size_t)nzj[k] * 128 + t];
        acc /= Z;
    } else {   // all-masked row -> uniform softmax over -1e9 scores
        for (int j = 0; j < NTT; j++) acc += Ht[(size_t)j * 128 + t];
        acc *= (1.f / 2048.f);
    }
    msgs[((size_t)p * NTT + i) * 128 + t] = f2b(acc);
}
// at1 lite: u = msgs@taW+tab precomputed by gemm_bat_k into ubuf (bf16).
__global__ __launch_bounds__(128) void at1_lite_k(const u16* __restrict__ msgs,
                                                  const u16* __restrict__ ubuf,
                                                  const u16* __restrict__ taq,
                                                  u16* __restrict__ X1) {
    int n = blockIdx.x, t1 = blockIdx.y, c = threadIdx.x;
    __shared__ float sv[6], red[2];
    float qcv = b2f(taq[t1 * 128 + c]);
    for (int t2 = 0; t2 < 6; t2++) {
        float u = b2f(ubuf[(((size_t)t1 * 6 + t2) * NTT + n) * 128 + c]);
        float s = bsum128(tanhf(u) * qcv, red);
        if (c == 0) sv[t2] = s;
    }
    __syncthreads();
    float mx = -3e38f;
    for (int t2 = 0; t2 < 6; t2++) mx = fmaxf(mx, sv[t2]);
    float z = 0.f;
    for (int t2 = 0; t2 < 6; t2++) z += expf(sv[t2] - mx);
    float o = 0.f;
    for (int t2 = 0; t2 < 6; t2++)
        o += expf(sv[t2] - mx) * b2f(msgs[(((size_t)t1 * 6 + t2) * NTT + n) * 128 + c]);
    o /= z;
    X1[((size_t)t1 * NTT + n) * 128 + c] = f2b(fmaxf(o, 0.f));
}
// dense hop-2 aggregation: adj dtype per flag
__global__ __launch_bounds__(128) void gc2_agg_k(const void* __restrict__ adjv,
                                                 size_t adjBase,
                                                 const float* __restrict__ hx,
                                                 const u16* __restrict__ bias,
                                                 float* __restrict__ msgs5,
                                                 const int* flagp) {
    int i = blockIdx.x, s = blockIdx.y, t = threadIdx.x;
    const bool f32 = flagp[0] != 0;
    size_t rowoff = adjBase + ((size_t)s * NTT + i) * NTT;
    __shared__ int nzj[2048];
    __shared__ float nzw[2048];
    __shared__ int cnt;
    if (t == 0) cnt = 0;
    __syncthreads();
    int j0 = t * 16;
    float av[16];
    if (f32) {
        const float4* af = (const float4*)((const float*)adjv + rowoff + j0);
#pragma unroll
        for (int q = 0; q < 4; q++) {
            float4 d = af[q];
            av[q * 4 + 0] = d.x; av[q * 4 + 1] = d.y;
            av[q * 4 + 2] = d.z; av[q * 4 + 3] = d.w;
        }
    } else {
        const u16* ab = (const u16*)adjv + rowoff + j0;
        union { uint4 v; u16 u[8]; } a0, a1;
        a0.v = *(const uint4*)(ab);
        a1.v = *(const uint4*)(ab + 8);
#pragma unroll
        for (int q = 0; q < 16; q++) av[q] = b2f(q < 8 ? a0.u[q] : a1.u[q - 8]);
    }
#pragma unroll
    for (int jj = 0; jj < 16; jj++) {
        if (av[jj] != 0.f) {
            int kk = atomicAdd(&cnt, 1);
            nzj[kk] = j0 + jj;
            nzw[kk] = av[jj];
        }
    }
    __syncthreads();
    const float* hxs = hx + (size_t)s * NTT * 128;
    float acc = 0.f;
    int nnz = cnt;
    for (int k = 0; k < nnz; k++) acc += nzw[k] * hxs[(size_t)nzj[k] * 128 + t];
    msgs5[((size_t)s * NTT + i) * 128 + t] = acc + b2f(bias[t]);
}
// at2 (ta index 11) + final linear + log_softmax -> FLOAT32 out [2048,4]
__global__ __launch_bounds__(128) void at2_head_k(const float* __restrict__ msgs5,
                                                  const u16* __restrict__ taW,
                                                  const u16* __restrict__ tab,
                                                  const u16* __restrict__ taq,
                                                  const u16* __restrict__ finW,
                                                  const u16* __restrict__ finb,
                                                  float* __restrict__ out) {
    int n = blockIdx.x, c = threadIdx.x;
    __shared__ float mr[6][128], sv[6], red[2];
    const u16* Wt = taW + (size_t)11 * 16384;
    float bc = b2f(tab[11 * 128 + c]), qcv = b2f(taq[11 * 128 + c]);
    for (int s = 0; s < 6; s++)
        mr[s][c] = msgs5[((size_t)s * NTT + n) * 128 + c];
    __syncthreads();
    for (int s = 0; s < 6; s++) {
        float u = bc;
        for (int k = 0; k < 128; k++) u += mr[s][k] * b2f(Wt[k * 128 + c]);
        float sc = bsum128(tanhf(u) * qcv, red);
        if (c == 0) sv[s] = sc;
    }
    __syncthreads();
    float mx = -3e38f;
    for (int s = 0; s < 6; s++) mx = fmaxf(mx, sv[s]);
    float z = 0.f;
    for (int s = 0; s < 6; s++) z += expf(sv[s] - mx);
    float x2c = 0.f;
    for (int s = 0; s < 6; s++) x2c += expf(sv[s] - mx) * mr[s][c];
    x2c /= z;   // no relu in at2
    float l0 = bsum128(x2c * b2f(finW[c * 4 + 0]), red) + b2f(finb[0]);
    float l1 = bsum128(x2c * b2f(finW[c * 4 + 1]), red) + b2f(finb[1]);
    float l2 = bsum128(x2c * b2f(finW[c * 4 + 2]), red) + b2f(finb[2]);
    float l3 = bsum128(x2c * b2f(finW[c * 4 + 3]), red) + b2f(finb[3]);
    float m4 = fmaxf(fmaxf(l0, l1), fmaxf(l2, l3));
    float ls = logf(expf(l0 - m4) + expf(l1 - m4) + expf(l2 - m4) + expf(l3 - m4)) + m4;
    if (c < 4) {
        float v = (c == 0) ? l0 : (c == 1) ? l1 : (c == 2) ? l2 : l3;
        out[n * 4 + c] = v - ls;   // FLOAT32 output (reference dtype)
    }
}

// ---------------------------------------------------------------------------
extern "C" void kernel_launch(void* const* d_in, const int* in_sizes, int n_in,
                              void* d_out, int out_size, void* d_ws, size_t ws_size,
                              hipStream_t stream) {
    const void* x       = d_in[0];
    const int* ei       = (const int*)d_in[1];
    const int* batch    = (const int*)d_in[2];
    const int* rootidx  = (const int*)d_in[3];
    const int* type_x0  = (const int*)d_in[4];
    const int* type_x1  = (const int*)d_in[5];
    const int* type_x2  = (const int*)d_in[6];
    const int* root1    = (const int*)d_in[7];
    const int* parent1  = (const int*)d_in[8];
    const int* root2    = (const int*)d_in[9];
    const int* parent2  = (const int*)d_in[10];
    const int* type_x3  = (const int*)d_in[11];
    const int* root3    = (const int*)d_in[12];
    const int* type_x4  = (const int*)d_in[13];
    const int* root4    = (const int*)d_in[14];
    const void* adj     = d_in[15];

    char* ws = (char*)d_ws;
    int*   flag = (int*)(ws);
    u16*   pb   = (u16*)  (ws + 64 * 1024);   // bf16 params (1.31 MB)
    float* dinv = (float*)(ws + 2 * MiB);
    u16*   xwb  = (u16*)  (ws + 3 * MiB);     // [N,128] bf16 -> [3, 51.83)
    float* h2   = (float*)(ws + 52 * MiB);    // [N,128] f32 -> [52, 149.66)
    u16*   h1r  = (u16*)  (ws + 52 * MiB);    // ALIASES h2 start; dead before
                                              // h2 is written (gather2)
    // CSR scratch @150+ (Phase G only; dead before Phase M's vb@150)
    int*   cnt_i   = (int*)(ws + 150 * MiB);  // [N] in-degree histogram
    int*   rowptr  = (int*)(ws + 151 * MiB);  // [N+1]
    int*   cursor  = (int*)(ws + 152 * MiB);  // [N]
    int*   csr_src = (int*)(ws + 153 * MiB);  // [E] (4 MB) -> [153, 157)
    int*   bsum    = (int*)(ws + 158 * MiB);  // [196]
    int*   bofs    = (int*)(ws + 158 * MiB + 4096);
    // Phase M aliases
    u16*   seqb = (u16*)  (ws + 3 * MiB);     // [61440,128] bf16
    u16*   qb   = (u16*)  (ws + 18 * MiB);
    u16*   kb   = (u16*)  (ws + 33 * MiB);
    u16*   vb   = (u16*)  (ws + 150 * MiB);
    u16*   aob  = (u16*)  (ws + 165 * MiB);
    u16*   seqo = (u16*)  (ws + 18 * MiB);    // alias qb (dead after mha)
    u16*   kpre = (u16*)  (ws + 33 * MiB);    // alias kb (dead after mha)
    u16*   x0b  = (u16*)  (ws + 180 * MiB);   // [6,2048,128] bf16
    u16*   X1b  = (u16*)  (ws + 183 * MiB);
    // Phase A aliases (h2 dead)
    float* Hb   = (float*)(ws + 52 * MiB);    // [6,2048,128] f32 [52,58)
    float* esrc = (float*)(ws + 58 * MiB);
    float* edst = (float*)(ws + 59 * MiB);
    u16*   msgs = (u16*)  (ws + 60 * MiB);    // [36,2048,128] bf16 [60,78)
    u16*   ubuf = (u16*)  (ws + 78 * MiB);    // [36,2048,128] bf16 [78,96)
    float* hx   = (float*)(ws + 96 * MiB);    // [96,102)
    float* msg5 = (float*)(ws + 102 * MiB);   // [102,108)

    // ------- dtype probe + param normalization -------
    probe_k<<<1, 256, 0, stream>>>(x, flag);
    CTab tb;
    int kk = 0;
    auto add = [&](int i, unsigned off, unsigned n) {
        tb.e[kk].src = d_in[i]; tb.e[kk].dstOff = off; tb.e[kk].cnt = n; kk++;
    };
    add(16, O_W1, 32768);   add(17, O_b1, 128);     add(18, O_W2, 32768);
    add(19, O_b2, 128);     add(20, O_mhaW, 131072);add(21, O_mhab, 1024);
    add(22, O_attWq, 65536);add(23, O_attWk, 65536);add(24, O_attv, 512);
    add(25, O_fuseW, 1024); add(26, O_fuseb, 4);    add(27, O_gatW, 98304);
    add(28, O_asrc, 4608);  add(29, O_adst, 4608);  add(30, O_taW, 196608);
    add(31, O_tab, 1536);   add(32, O_taq, 1536);   add(33, O_gc2W, 16384);
    add(34, O_gc2b, 128);   add(35, O_finW, 512);   add(36, O_finb, 4);
    convp_k<<<256, 256, 0, stream>>>(tb, pb, flag);

    // ---------------- Phase G: CSR build (once) + two GCN layers -----------
    const int NB = (NNODE + 1023) / 1024;   // 196 scan blocks
    hipMemsetAsync(cnt_i, 0, (size_t)NNODE * 4, stream);
    hist_k<<<(NEDGE + 255) / 256, 256, 0, stream>>>(ei, cnt_i);
    dinv_k<<<(NNODE + 255) / 256, 256, 0, stream>>>(cnt_i, dinv);
    scan1_k<<<NB, 256, 0, stream>>>(cnt_i, bsum);
    scan2_k<<<1, 64, 0, stream>>>(bsum, bofs, NB, rowptr + NNODE);
    scan3_k<<<NB, 256, 0, stream>>>(cnt_i, bofs, rowptr, cursor);
    fill_k<<<(NEDGE + 255) / 256, 256, 0, stream>>>(ei, cursor, csr_src);

    gemm_bf16<256, true><<<(NNODE + 127) / 128, 256, 0, stream>>>(x, pb + O_W1, (const u16*)nullptr, xwb, NNODE, flag);
    gather_gcn_k<true><<<(NNODE + 3) / 4, 256, 0, stream>>>(xwb, rowptr, csr_src, dinv, pb + O_b1, h1r);

    gemm_conv2<<<(NNODE + 127) / 128, 256, 0, stream>>>(h1r, batch, rootidx, pb + O_W2, xwb, NNODE);
    gather_gcn_k<false><<<(NNODE + 3) / 4, 256, 0, stream>>>(xwb, rowptr, csr_src, dinv, pb + O_b2, h2);

    // ---------------- Phase M: build x0[0..5] ----------------
    x0copy_k<<<(NTT * 128) / 256, 256, 0, stream>>>(h2, type_x0, x0b);
    addatt12_k<<<NTT, 128, 0, stream>>>(h2, type_x1, root1, parent1,
                                        pb + O_attWq, pb + O_attWk, pb + O_attv,
                                        pb + O_fuseW, pb + O_fuseb, 0,
                                        x0b + 1 * NTT * 128);
    addatt12_k<<<NTT, 128, 0, stream>>>(h2, type_x2, root2, parent2,
                                        pb + O_attWq + 16384, pb + O_attWk + 16384,
                                        pb + O_attv + 128, pb + O_fuseW + 256,
                                        pb + O_fuseb, 1,
                                        x0b + 2 * NTT * 128);
    for (int i = 0; i < 2; i++) {
        int L = i ? 30 : 13;
        const int* tx = i ? type_x4 : type_x3;
        const int* rt = i ? root4 : root3;
        int M = NTT * L;
        gather_seq_k<<<(M * 128 + 255) / 256, 256, 0, stream>>>(h2, tx, seqb, M * 128);
        gemm_bf16<128, true><<<(M + 127) / 128, 256, 0, stream>>>(seqb, pb + O_mhaW + (i * 4 + 0) * 16384,
                                                                  pb + O_mhab + (i * 4 + 0) * 128, qb, M, nullptr);
        gemm_bf16<128, true><<<(M + 127) / 128, 256, 0, stream>>>(seqb, pb + O_mhaW + (i * 4 + 1) * 16384,
                                                                  pb + O_mhab + (i * 4 + 1) * 128, kb, M, nullptr);
        gemm_bf16<128, true><<<(M + 127) / 128, 256, 0, stream>>>(seqb, pb + O_mhaW + (i * 4 + 2) * 16384,
                                                                  pb + O_mhab + (i * 4 + 2) * 128, vb, M, nullptr);
        mha_attn_k<<<dim3(NTT, 8), 64, 0, stream>>>(qb, kb, vb, aob, L);
        gemm_bf16<128, true><<<(M + 127) / 128, 256, 0, stream>>>(aob, pb + O_mhaW + (i * 4 + 3) * 16384,
                                                                  pb + O_mhab + (i * 4 + 3) * 128, seqo, M, nullptr);
        // kpre = seqo @ attWk (no bias in _add_att); kb region dead after mha
        gemm_bf16<128, true><<<(M + 127) / 128, 256, 0, stream>>>(seqo, pb + O_attWk + (2 + i) * 16384,
                                                                  (const u16*)nullptr, kpre, M, nullptr);
        addatt_root_k<<<NTT, 128, 0, stream>>>(seqo, kpre, h2, rt,
                                               pb + O_attWq + (2 + i) * 16384,
                                               pb + O_attv + (2 + i) * 128,
                                               pb + O_fuseW + (2 + i) * 256,
                                               pb + O_fuseb, 2 + i, L,
                                               x0b + (3 + i) * NTT * 128);
    }

    // ---------------- Phase A: hetero GAT + heads ----------------
    // 6 gat GEMMs in one batched launch (grid.y = type)
    gemm_bat_k<128, false><<<dim3(NTT / 128, 6), 256, 0, stream>>>(
        x0b, (size_t)NTT * 128, pb + O_gatW, 16384, (const u16*)nullptr, 0,
        Hb, (size_t)NTT * 128, NTT);
    gat_e_k<<<dim3(16, 36), 128, 0, stream>>>(Hb, pb + O_asrc, pb + O_adst, esrc, edst);
    gc1_attn_k<<<dim3(NTT, 36), 128, 0, stream>>>(adj, Hb, esrc, edst, msgs, flag);
    // at1: u = msgs @ taW[t1] + tab[t1] for all 6 t1 (one MFMA launch)
    gemm_bat_k<128, true><<<dim3((6 * NTT) / 128, 6), 256, 0, stream>>>(
        msgs, (size_t)6 * NTT * 128, pb + O_taW, 16384, pb + O_tab, 128,
        ubuf, (size_t)6 * NTT * 128, 6 * NTT);
    at1_lite_k<<<dim3(NTT, 6), 128, 0, stream>>>(msgs, ubuf, pb + O_taq, X1b);
    gemm_bf16<128, false><<<(6 * NTT) / 128, 256, 0, stream>>>(X1b, pb + O_gc2W, (const u16*)nullptr, hx, 6 * NTT, nullptr);
    gc2_agg_k<<<dim3(NTT, 6), 128, 0, stream>>>(adj, (size_t)5 * 6 * NTT * NTT, hx,
                                                pb + O_gc2b, msg5, flag);
    at2_head_k<<<NTT, 128, 0, stream>>>(msg5, pb + O_taW, pb + O_tab, pb + O_taq,
                                        pb + O_finW, pb + O_finb, (float*)d_out);
}

// Round 5
// 2000.688 us; speedup vs baseline: 2.2146x; 1.1325x over previous
//
#include <hip/hip_runtime.h>
#include <hip/hip_bf16.h>
#include <math.h>

// ---------------------------------------------------------------------------
// MHGAT forward on MI355X (gfx950). Inputs/adj are float32 (auto-detected vs
// bf16 by probe_k); weights normalized into a bf16 params block; GEMM B-side
// weights additionally pre-TRANSPOSED (pbT) so LDS staging is coalesced.
// OUTPUT IS FLOAT32 [2048,4].
// Workspace (MiB offsets), PEAK ~187.2 MiB:
//  flag@0 | pb bf16 params @64KiB (1.3MB) | dinv@2 | xwb@3(49)
//  h1r@52(49, ALIASES h2 start: dead before h2 written) | h2 f32@52(98)
//  CSR (Phase G only): cnt@150 rowptr@151 cursor@152 csr_src@153(4)
//    bsum/bofs@158
//  Phase M: seqb@3(15) qb@18 kb@33 vb@150 aob@165 seqo=qb kpre@33 (kb dead)
//           x0b@180(3) X1b@183(3)
//  Phase A: Hb@52(6) esrc@58 edst@59 msgs bf16@60(18) ubuf bf16@78(18)
//           hx@96(6) msg5@102(6) ubuf2@60(3, over dead msgs)
//  pbT (transposed weights, all phases) @186 (1.15MB)
// ---------------------------------------------------------------------------

typedef unsigned short u16;
typedef unsigned int   u32;
typedef __attribute__((ext_vector_type(8))) short short8;   // 8 x bf16
typedef __attribute__((ext_vector_type(4))) float f32x4;

#define NNODE 200000
#define NEDGE 1000000
#define NTT   2048

static constexpr size_t MiB = 1024ull * 1024ull;

// params block element offsets (bf16)
enum : unsigned {
    O_W1 = 0,         O_b1 = 32768,     O_W2 = 32896,     O_b2 = 65664,
    O_mhaW = 65792,   O_mhab = 196864,  O_attWq = 197888, O_attWk = 263424,
    O_attv = 328960,  O_fuseW = 329472, O_fuseb = 330496, O_gatW = 330504,
    O_asrc = 428808,  O_adst = 433416,  O_taW = 438024,   O_tab = 634632,
    O_taq = 636168,   O_gc2W = 637704,  O_gc2b = 654088,  O_finW = 654216,
    O_finb = 654728
};
// transposed (B-side) weight offsets in pbT: layout [mat][n][k]
enum : unsigned {
    T_W1 = 0,          T_W2 = 32768,     T_mhaW = 65536,   T_attWk = 196608,
    T_gatW = 262144,   T_taW = 360448,   T_gc2W = 557056   // total 573440
};

__device__ __forceinline__ float b2f(u16 u) { return __uint_as_float(((u32)u) << 16); }
__device__ __forceinline__ u16 f2b(float f) {
    u32 u = __float_as_uint(f);
    u32 r = (u + 0x7fffu + ((u >> 16) & 1u)) >> 16;   // RNE
    return (u16)r;
}

__device__ __forceinline__ float wsum(float v) {
#pragma unroll
    for (int m = 1; m < 64; m <<= 1) v += __shfl_xor(v, m, 64);
    return v;
}
__device__ __forceinline__ float bsum128(float v, float* s) {
    v = wsum(v);
    __syncthreads();
    if ((threadIdx.x & 63) == 0) s[threadIdx.x >> 6] = v;
    __syncthreads();
    return s[0] + s[1];
}
__device__ __forceinline__ float bmax128(float v, float* s) {
#pragma unroll
    for (int m = 1; m < 64; m <<= 1) v = fmaxf(v, __shfl_xor(v, m, 64));
    __syncthreads();
    if ((threadIdx.x & 63) == 0) s[threadIdx.x >> 6] = v;
    __syncthreads();
    return fmaxf(s[0], s[1]);
}

// ------------------------ dtype probe + param convert ----------------------
__global__ __launch_bounds__(256) void probe_k(const void* xsrc, int* flag) {
    __shared__ int cnt;
    if (threadIdx.x == 0) cnt = 0;
    __syncthreads();
    int c = 0;
    for (int i = threadIdx.x; i < 4096; i += 256) {
        float v = fabsf(b2f(((const u16*)xsrc)[2 * i]));
        if (v > 1e-6f && v < 100.f) c++;
    }
    atomicAdd(&cnt, c);
    __syncthreads();
    if (threadIdx.x == 0) {
        flag[0] = (cnt < 2048) ? 1 : 0;
        flag[1] = 1;   // constant-1 for forcing the f32-A GEMM path
    }
}

struct CEnt { const void* src; unsigned dstOff; unsigned cnt; };
struct CTab { CEnt e[21]; };
struct TEnt { const void* src; unsigned dstOff; unsigned cnt; int msh; int ksh; };
struct TTab { TEnt e[7]; };
__global__ __launch_bounds__(256) void convp_k(CTab tb, TTab tt, u16* pb, u16* pbT,
                                               const int* flag) {
    bool f32 = flag[0] != 0;
    int stride = gridDim.x * blockDim.x;
    int tid = blockIdx.x * blockDim.x + threadIdx.x;
    for (int k = 0; k < 21; k++) {
        const void* s = tb.e[k].src;
        unsigned off = tb.e[k].dstOff, n = tb.e[k].cnt;
        for (unsigned i = tid; i < n; i += stride)
            pb[off + i] = f32 ? f2b(((const float*)s)[i]) : ((const u16*)s)[i];
    }
    // transposed copies for GEMM B staging: src [mat][k][n] -> dst [mat][n][k]
    for (int k = 0; k < 7; k++) {
        const void* s = tt.e[k].src;
        unsigned off = tt.e[k].dstOff, n = tt.e[k].cnt;
        int msh = tt.e[k].msh, ksh = tt.e[k].ksh;
        for (unsigned i = tid; i < n; i += stride) {
            unsigned mat = i >> msh, r = i & ((1u << msh) - 1);
            unsigned kk = r >> 7, nn = r & 127;
            unsigned dst = (mat << msh) + (nn << ksh) + kk;
            pbT[off + dst] = f32 ? f2b(((const float*)s)[i]) : ((const u16*)s)[i];
        }
    }
}

// ---------------------------------------------------------------------------
// bf16 GEMM: C[M,128] = A[M,K] @ W[K,128] (+bias). MFMA 16x16x32.
// WT is the TRANSPOSED weight [128][K] -> coalesced uint4 B staging.
// A may be raw f32 (flagp!=null && *flagp) or bf16.
// ---------------------------------------------------------------------------
template <int K, bool OBF>
__global__ __launch_bounds__(256) void gemm_bf16(const void* __restrict__ A,
                                                 const u16* __restrict__ WT,
                                                 const u16* __restrict__ bias,
                                                 void* __restrict__ Cv, int M,
                                                 const int* flagp) {
    constexpr int LW = 40;
    __shared__ u16 Al[128 * LW];
    __shared__ u16 Bl[128 * LW];   // Bl[n*LW + k]
    const int tid = threadIdx.x;
    const int lane = tid & 63, wv = tid >> 6;
    const int row0 = blockIdx.x * 128;
    const int m16 = lane & 15, oct = lane >> 4;
    const bool aF32 = flagp && (flagp[0] != 0);

    f32x4 acc[2][8];
#pragma unroll
    for (int s = 0; s < 2; s++)
#pragma unroll
        for (int t = 0; t < 8; t++) acc[s][t] = (f32x4){0.f, 0.f, 0.f, 0.f};

    const int r = tid >> 1, kk16 = (tid & 1) * 16;
    const int gr = row0 + r;
    const bool rowOk = (gr < M);

    for (int k0 = 0; k0 < K; k0 += 32) {
        {
            uint4 d0 = {0, 0, 0, 0}, d1 = {0, 0, 0, 0};
            if (rowOk) {
                if (aF32) {
                    const float4* s4 = (const float4*)((const float*)A + (size_t)gr * K + k0 + kk16);
                    union { uint4 v[2]; u16 u[16]; } t;
#pragma unroll
                    for (int q = 0; q < 4; q++) {
                        float4 f = s4[q];
                        t.u[q * 4 + 0] = f2b(f.x); t.u[q * 4 + 1] = f2b(f.y);
                        t.u[q * 4 + 2] = f2b(f.z); t.u[q * 4 + 3] = f2b(f.w);
                    }
                    d0 = t.v[0];
                    d1 = t.v[1];
                } else {
                    const uint4* src = (const uint4*)((const u16*)A + (size_t)gr * K + k0 + kk16);
                    d0 = src[0];
                    d1 = src[1];
                }
            }
            *(uint4*)&Al[r * LW + kk16] = d0;
            *(uint4*)&Al[r * LW + kk16 + 8] = d1;
        }
        {   // coalesced B staging from transposed weight (r is n here)
            const uint4* wsrc = (const uint4*)(WT + (size_t)r * K + k0 + kk16);
            *(uint4*)&Bl[r * LW + kk16] = wsrc[0];
            *(uint4*)&Bl[r * LW + kk16 + 8] = wsrc[1];
        }
        __syncthreads();

        short8 af0 = *(const short8*)&Al[(wv * 32 + m16) * LW + oct * 8];
        short8 af1 = *(const short8*)&Al[(wv * 32 + 16 + m16) * LW + oct * 8];
        short8 bf[8];
#pragma unroll
        for (int t = 0; t < 8; t++)
            bf[t] = *(const short8*)&Bl[(t * 16 + m16) * LW + oct * 8];
#pragma unroll
        for (int t = 0; t < 8; t++) {
            acc[0][t] = __builtin_amdgcn_mfma_f32_16x16x32_bf16(af0, bf[t], acc[0][t], 0, 0, 0);
            acc[1][t] = __builtin_amdgcn_mfma_f32_16x16x32_bf16(af1, bf[t], acc[1][t], 0, 0, 0);
        }
        __syncthreads();
    }

    float bv[8];
#pragma unroll
    for (int t = 0; t < 8; t++) bv[t] = bias ? b2f(bias[t * 16 + m16]) : 0.f;
#pragma unroll
    for (int s = 0; s < 2; s++)
#pragma unroll
        for (int t = 0; t < 8; t++)
#pragma unroll
            for (int rr = 0; rr < 4; rr++) {
                int orow = row0 + wv * 32 + s * 16 + oct * 4 + rr;
                if (orow < M) {
                    float val = acc[s][t][rr] + bv[t];
                    size_t idx = (size_t)orow * 128 + t * 16 + m16;
                    if (OBF) ((u16*)Cv)[idx] = f2b(val);
                    else     ((float*)Cv)[idx] = val;
                }
            }
}

// Batched variant: blockIdx.y selects slab with strides. A bf16. WT transposed.
template <int K, bool OBF>
__global__ __launch_bounds__(256) void gemm_bat_k(const u16* __restrict__ A0, size_t Astride,
                                                  const u16* __restrict__ W0, unsigned Wstride,
                                                  const u16* __restrict__ bias0, unsigned bStride,
                                                  void* __restrict__ Cv, size_t Cstride,
                                                  int M) {
    constexpr int LW = 40;
    __shared__ u16 Al[128 * LW];
    __shared__ u16 Bl[128 * LW];
    const int y = blockIdx.y;
    const u16* A = A0 + (size_t)y * Astride;
    const u16* WT = W0 + (size_t)y * Wstride;
    const u16* bias = bias0 ? (bias0 + (size_t)y * bStride) : nullptr;
    const size_t cbase = (size_t)y * Cstride;
    const int tid = threadIdx.x;
    const int lane = tid & 63, wv = tid >> 6;
    const int row0 = blockIdx.x * 128;
    const int m16 = lane & 15, oct = lane >> 4;

    f32x4 acc[2][8];
#pragma unroll
    for (int s = 0; s < 2; s++)
#pragma unroll
        for (int t = 0; t < 8; t++) acc[s][t] = (f32x4){0.f, 0.f, 0.f, 0.f};

    const int r = tid >> 1, kk16 = (tid & 1) * 16;
    const int gr = row0 + r;
    const bool rowOk = (gr < M);

    for (int k0 = 0; k0 < K; k0 += 32) {
        {
            uint4 d0 = {0, 0, 0, 0}, d1 = {0, 0, 0, 0};
            if (rowOk) {
                const uint4* src = (const uint4*)(A + (size_t)gr * K + k0 + kk16);
                d0 = src[0];
                d1 = src[1];
            }
            *(uint4*)&Al[r * LW + kk16] = d0;
            *(uint4*)&Al[r * LW + kk16 + 8] = d1;
        }
        {
            const uint4* wsrc = (const uint4*)(WT + (size_t)r * K + k0 + kk16);
            *(uint4*)&Bl[r * LW + kk16] = wsrc[0];
            *(uint4*)&Bl[r * LW + kk16 + 8] = wsrc[1];
        }
        __syncthreads();

        short8 af0 = *(const short8*)&Al[(wv * 32 + m16) * LW + oct * 8];
        short8 af1 = *(const short8*)&Al[(wv * 32 + 16 + m16) * LW + oct * 8];
        short8 bf[8];
#pragma unroll
        for (int t = 0; t < 8; t++)
            bf[t] = *(const short8*)&Bl[(t * 16 + m16) * LW + oct * 8];
#pragma unroll
        for (int t = 0; t < 8; t++) {
            acc[0][t] = __builtin_amdgcn_mfma_f32_16x16x32_bf16(af0, bf[t], acc[0][t], 0, 0, 0);
            acc[1][t] = __builtin_amdgcn_mfma_f32_16x16x32_bf16(af1, bf[t], acc[1][t], 0, 0, 0);
        }
        __syncthreads();
    }

    float bv[8];
#pragma unroll
    for (int t = 0; t < 8; t++) bv[t] = bias ? b2f(bias[t * 16 + m16]) : 0.f;
#pragma unroll
    for (int s = 0; s < 2; s++)
#pragma unroll
        for (int t = 0; t < 8; t++)
#pragma unroll
            for (int rr = 0; rr < 4; rr++) {
                int orow = row0 + wv * 32 + s * 16 + oct * 4 + rr;
                if (orow < M) {
                    float val = acc[s][t][rr] + bv[t];
                    size_t idx = cbase + (size_t)orow * 128 + t * 16 + m16;
                    if (OBF) ((u16*)Cv)[idx] = f2b(val);
                    else     ((float*)Cv)[idx] = val;
                }
            }
}

// conv2 GEMM: A row i = concat(h1r[i], h1r[root(i)]) staged on the fly. K=256.
__global__ __launch_bounds__(256) void gemm_conv2(const u16* __restrict__ h1r,
                                                  const int* __restrict__ batch,
                                                  const int* __restrict__ rootindex,
                                                  const u16* __restrict__ WT,
                                                  u16* __restrict__ C, int M) {
    constexpr int LW = 40;
    __shared__ u16 Al[128 * LW];
    __shared__ u16 Bl[128 * LW];
    const int tid = threadIdx.x;
    const int lane = tid & 63, wv = tid >> 6;
    const int row0 = blockIdx.x * 128;
    const int m16 = lane & 15, oct = lane >> 4;

    f32x4 acc[2][8];
#pragma unroll
    for (int s = 0; s < 2; s++)
#pragma unroll
        for (int t = 0; t < 8; t++) acc[s][t] = (f32x4){0.f, 0.f, 0.f, 0.f};

    const int r = tid >> 1, kk16 = (tid & 1) * 16;
    const int gr = row0 + r;
    const u16* pSelf = nullptr; const u16* pRoot = nullptr;
    if (gr < M) {
        pSelf = h1r + (size_t)gr * 128;
        pRoot = h1r + (size_t)rootindex[batch[gr]] * 128;
    }

    for (int k0 = 0; k0 < 256; k0 += 32) {
        {
            int kg = k0 + kk16;   // chunk never straddles the 128 boundary
            uint4 d0 = {0, 0, 0, 0}, d1 = {0, 0, 0, 0};
            if (pSelf) {
                const u16* sp = (kg < 128) ? (pSelf + kg) : (pRoot + kg - 128);
                d0 = ((const uint4*)sp)[0];
                d1 = ((const uint4*)sp)[1];
            }
            *(uint4*)&Al[r * LW + kk16] = d0;
            *(uint4*)&Al[r * LW + kk16 + 8] = d1;
        }
        {
            const uint4* wsrc = (const uint4*)(WT + (size_t)r * 256 + k0 + kk16);
            *(uint4*)&Bl[r * LW + kk16] = wsrc[0];
            *(uint4*)&Bl[r * LW + kk16 + 8] = wsrc[1];
        }
        __syncthreads();

        short8 af0 = *(const short8*)&Al[(wv * 32 + m16) * LW + oct * 8];
        short8 af1 = *(const short8*)&Al[(wv * 32 + 16 + m16) * LW + oct * 8];
        short8 bf[8];
#pragma unroll
        for (int t = 0; t < 8; t++)
            bf[t] = *(const short8*)&Bl[(t * 16 + m16) * LW + oct * 8];
#pragma unroll
        for (int t = 0; t < 8; t++) {
            acc[0][t] = __builtin_amdgcn_mfma_f32_16x16x32_bf16(af0, bf[t], acc[0][t], 0, 0, 0);
            acc[1][t] = __builtin_amdgcn_mfma_f32_16x16x32_bf16(af1, bf[t], acc[1][t], 0, 0, 0);
        }
        __syncthreads();
    }
#pragma unroll
    for (int s = 0; s < 2; s++)
#pragma unroll
        for (int t = 0; t < 8; t++)
#pragma unroll
            for (int rr = 0; rr < 4; rr++) {
                int orow = row0 + wv * 32 + s * 16 + oct * 4 + rr;
                if (orow < M)
                    C[(size_t)orow * 128 + t * 16 + m16] = f2b(acc[s][t][rr]);
            }
}

// --------------------------- GCN via CSR gather ----------------------------
__global__ __launch_bounds__(256) void hist_k(const int* __restrict__ ei,
                                              int* __restrict__ cnt) {
    int e = blockIdx.x * 256 + threadIdx.x;
    if (e < NEDGE) atomicAdd(&cnt[ei[NEDGE + e]], 1);
}
__global__ __launch_bounds__(256) void scan1_k(const int* __restrict__ cnt,
                                               int* __restrict__ bsum) {
    int t = threadIdx.x;
    int base = blockIdx.x * 1024 + t * 4;
    int s = 0;
#pragma unroll
    for (int q = 0; q < 4; q++) {
        int i = base + q;
        if (i < NNODE) s += cnt[i];
    }
#pragma unroll
    for (int m = 1; m < 64; m <<= 1) s += __shfl_xor(s, m, 64);
    __shared__ int ws_[4];
    if ((t & 63) == 0) ws_[t >> 6] = s;
    __syncthreads();
    if (t == 0) bsum[blockIdx.x] = ws_[0] + ws_[1] + ws_[2] + ws_[3];
}
__global__ __launch_bounds__(64) void scan2_k(const int* __restrict__ bsum,
                                              int* __restrict__ bofs, int nb,
                                              int* __restrict__ rowptrN) {
    if (threadIdx.x == 0) {
        int r = 0;
        for (int i = 0; i < nb; i++) { int v = bsum[i]; bofs[i] = r; r += v; }
        *rowptrN = r;
    }
}
// exclusive scan within chunk + block offset -> rowptr,cursor; also dinv.
__global__ __launch_bounds__(256) void scan3_k(const int* __restrict__ cnt,
                                               const int* __restrict__ bofs,
                                               int* __restrict__ rowptr,
                                               int* __restrict__ cursor,
                                               float* __restrict__ dinv) {
    int t = threadIdx.x, lane = t & 63, wv = t >> 6;
    int base = blockIdx.x * 1024 + t * 4;
    int v[4];
    int s = 0;
#pragma unroll
    for (int q = 0; q < 4; q++) {
        int i = base + q;
        v[q] = (i < NNODE) ? cnt[i] : 0;
        s += v[q];
    }
    int inc = s;
#pragma unroll
    for (int d = 1; d < 64; d <<= 1) {
        int u = __shfl_up(inc, d, 64);
        if (lane >= d) inc += u;
    }
    __shared__ int wsum_[4];
    if (lane == 63) wsum_[wv] = inc;
    __syncthreads();
    int wofs = 0;
    for (int w = 0; w < wv; w++) wofs += wsum_[w];
    int ex = bofs[blockIdx.x] + wofs + inc - s;
#pragma unroll
    for (int q = 0; q < 4; q++) {
        int i = base + q;
        if (i < NNODE) {
            rowptr[i] = ex;
            cursor[i] = ex;
            dinv[i] = rsqrtf((float)(v[q] + 1));   // deg = indeg + self loop
        }
        ex += v[q];
    }
}
__global__ __launch_bounds__(256) void fill_k(const int* __restrict__ ei,
                                              int* __restrict__ cursor,
                                              int* __restrict__ csr_src) {
    int e = blockIdx.x * 256 + threadIdx.x;
    if (e < NEDGE) {
        int col = ei[NEDGE + e];
        int pos = atomicAdd(&cursor[col], 1);
        csr_src[pos] = ei[e];
    }
}
// one wave per node: gather in-edges, f32 accumulate, fused bias+relu.
template <bool OBF>
__global__ __launch_bounds__(256) void gather_gcn_k(const u16* __restrict__ xwb,
                                                    const int* __restrict__ rowptr,
                                                    const int* __restrict__ csr_src,
                                                    const float* __restrict__ dinv,
                                                    const u16* __restrict__ bias,
                                                    void* __restrict__ out) {
    int node = blockIdx.x * 4 + (threadIdx.x >> 6);
    if (node >= NNODE) return;
    int lane = threadIdx.x & 63;
    int beg = rowptr[node], end = rowptr[node + 1];
    int cnt = end - beg;
    if (cnt < 0) cnt = 0;
    if (cnt > 2048) cnt = 2048;   // defensive bound (hangs kill containers)
    end = beg + cnt;
    float di = dinv[node];
    u32 pk = *(const u32*)&xwb[(size_t)node * 128 + lane * 2];
    float selfn = di * di;
    float a0 = b2f((u16)(pk & 0xffffu)) * selfn;
    float a1 = b2f((u16)(pk >> 16)) * selfn;
    int myrow = 0; float mynrm = 0.f;
    if (lane < cnt) {
        myrow = csr_src[beg + lane];
        mynrm = dinv[myrow] * di;
    }
    int n0 = cnt < 64 ? cnt : 64;
    for (int j = 0; j < n0; j++) {
        int row = __shfl(myrow, j, 64);
        float nrm = __shfl(mynrm, j, 64);
        u32 p2 = *(const u32*)&xwb[(size_t)row * 128 + lane * 2];
        a0 += b2f((u16)(p2 & 0xffffu)) * nrm;
        a1 += b2f((u16)(p2 >> 16)) * nrm;
    }
    for (int j = beg + 64; j < end; j++) {
        int row = csr_src[j];
        float nrm = dinv[row] * di;
        u32 p2 = *(const u32*)&xwb[(size_t)row * 128 + lane * 2];
        a0 += b2f((u16)(p2 & 0xffffu)) * nrm;
        a1 += b2f((u16)(p2 >> 16)) * nrm;
    }
    a0 = fmaxf(a0 + b2f(bias[lane * 2]), 0.f);
    a1 = fmaxf(a1 + b2f(bias[lane * 2 + 1]), 0.f);
    if (OBF) {
        u32 w = (u32)f2b(a0) | ((u32)f2b(a1) << 16);
        *(u32*)&((u16*)out)[(size_t)node * 128 + lane * 2] = w;
    } else {
        float* op = (float*)out + (size_t)node * 128 + lane * 2;
        op[0] = a0;
        op[1] = a1;
    }
}

// ------------------------- NT-side kernels ---------------------------------
__global__ __launch_bounds__(256) void x0copy_k(const float* h2, const int* tx, u16* x0) {
    int idx = blockIdx.x * 256 + threadIdx.x;   // NTT*128 total
    int n = idx >> 7, c = idx & 127;
    u16 v = f2b(h2[(size_t)tx[n] * 128 + c]);
    x0[idx] = v;
    x0[5 * NTT * 128 + idx] = v;
}
__global__ __launch_bounds__(256) void gather_seq_k(const float* h2, const int* tx,
                                                    u16* seqb, int total) {
    int idx = blockIdx.x * 256 + threadIdx.x;
    if (idx >= total) return;
    int node = tx[idx >> 7];
    seqb[idx] = f2b(h2[(size_t)node * 128 + (idx & 127)]);
}
__global__ __launch_bounds__(128) void addatt12_k(const float* __restrict__ h2,
                                                  const int* tx, const int* rid, const int* pid,
                                                  const u16* __restrict__ Wq,
                                                  const u16* __restrict__ Wk,
                                                  const u16* __restrict__ vv,
                                                  const u16* __restrict__ fw,
                                                  const u16* fbp, int fbi,
                                                  u16* __restrict__ out) {
    int n = blockIdx.x, c = threadIdx.x;
    __shared__ float ls[128], pr[128], rt[128], red[2];
    ls[c] = h2[(size_t)tx[n] * 128 + c];
    pr[c] = h2[(size_t)pid[n] * 128 + c];
    rt[c] = h2[(size_t)rid[n] * 128 + c];
    __syncthreads();
    float qc = 0.f;
    for (int k = 0; k < 128; k++) qc += ls[k] * b2f(Wq[k * 128 + c]);
    float vc = b2f(vv[c]);
    float u0 = qc, u1 = qc;
    for (int k = 0; k < 128; k++) {
        float wk = b2f(Wk[k * 128 + c]);
        u0 += pr[k] * wk;
        u1 += rt[k] * wk;
    }
    float s0 = bsum128(tanhf(u0) * vc, red);
    float s1 = bsum128(tanhf(u1) * vc, red);
    float mx = fmaxf(s0, s1);
    float e0 = expf(s0 - mx), e1 = expf(s1 - mx);
    float iz = 1.f / (e0 + e1);
    float att = (e0 * pr[c] + e1 * rt[c]) * iz;
    float pa = ls[c] * b2f(fw[c]) + att * b2f(fw[128 + c]);
    float alpha = 1.f / (1.f + expf(-(bsum128(pa, red) + b2f(fbp[fbi]))));
    out[(size_t)n * 128 + c] = f2b(alpha * ls[c] + (1.f - alpha) * att);
}
__global__ __launch_bounds__(64) void mha_attn_k(const u16* __restrict__ q,
                                                 const u16* __restrict__ k,
                                                 const u16* __restrict__ v,
                                                 u16* __restrict__ ao, int L) {
    int n = blockIdx.x, h = blockIdx.y, t = threadIdx.x;
    __shared__ float qs[30][16], ks[30][16], vs[30][16], sc[30][30];
    for (int e = t; e < L * 16; e += 64) {
        int l = e >> 4, d = e & 15;
        size_t base = ((size_t)n * L + l) * 128 + h * 16 + d;
        qs[l][d] = b2f(q[base]);
        ks[l][d] = b2f(k[base]);
        vs[l][d] = b2f(v[base]);
    }
    __syncthreads();
    for (int e = t; e < L * L; e += 64) {
        int l = e / L, m = e % L;
        float s = 0.f;
#pragma unroll
        for (int d = 0; d < 16; d++) s += qs[l][d] * ks[m][d];
        sc[l][m] = s * 0.25f;   // 1/sqrt(16)
    }
    __syncthreads();
    if (t < L) {
        float mx = -3e38f;
        for (int m = 0; m < L; m++) mx = fmaxf(mx, sc[t][m]);
        float z = 0.f;
        for (int m = 0; m < L; m++) { float w = expf(sc[t][m] - mx); sc[t][m] = w; z += w; }
        float izz = 1.f / z;
        for (int m = 0; m < L; m++) sc[t][m] *= izz;
    }
    __syncthreads();
    for (int e = t; e < L * 16; e += 64) {
        int l = e >> 4, d = e & 15;
        float o = 0.f;
        for (int m = 0; m < L; m++) o += sc[l][m] * vs[m][d];
        ao[((size_t)n * L + l) * 128 + h * 16 + d] = f2b(o);
    }
}
// addatt_root with precomputed kpre = seqo @ Wk (GEMM).
__global__ __launch_bounds__(128) void addatt_root_k(const u16* __restrict__ seqo,
                                                     const u16* __restrict__ kpre,
                                                     const float* __restrict__ h2,
                                                     const int* rid,
                                                     const u16* __restrict__ Wq,
                                                     const u16* __restrict__ vv,
                                                     const u16* __restrict__ fw,
                                                     const u16* fbp, int fbi, int L,
                                                     u16* __restrict__ out) {
    int n = blockIdx.x, c = threadIdx.x;
    __shared__ float rt[128], sl[32], red[2];
    rt[c] = h2[(size_t)rid[n] * 128 + c];
    __syncthreads();
    float qc = 0.f;
    for (int k = 0; k < 128; k++) qc += rt[k] * b2f(Wq[k * 128 + c]);
    float vc = b2f(vv[c]);
    for (int l = 0; l < L; l++) {
        float u = qc + b2f(kpre[((size_t)n * L + l) * 128 + c]);
        float s = bsum128(tanhf(u) * vc, red);
        if (c == 0) sl[l] = s;
    }
    __syncthreads();
    float mx = -3e38f;
    for (int l = 0; l < L; l++) mx = fmaxf(mx, sl[l]);
    float z = 0.f;
    for (int l = 0; l < L; l++) z += expf(sl[l] - mx);
    float att = 0.f;
    for (int l = 0; l < L; l++)
        att += expf(sl[l] - mx) * b2f(seqo[((size_t)n * L + l) * 128 + c]);
    att /= z;
    float pa = rt[c] * b2f(fw[c]) + att * b2f(fw[128 + c]);
    float alpha = 1.f / (1.f + expf(-(bsum128(pa, red) + b2f(fbp[fbi]))));
    out[(size_t)n * 128 + c] = f2b(alpha * rt[c] + (1.f - alpha) * att);
}
// gat scores, 4 threads/row for occupancy; float4 loads + shfl reduce.
__global__ __launch_bounds__(128) void gat_e2_k(const float* __restrict__ H,
                                                const u16* __restrict__ asrc,
                                                const u16* __restrict__ adst,
                                                float* esrc, float* edst) {
    int p = blockIdx.y, t1 = p / 6, t2 = p % 6;
    int t = threadIdx.x;
    __shared__ float vs[128], vd[128];
    vs[t] = b2f(asrc[p * 128 + t]);
    vd[t] = b2f(adst[p * 128 + t]);
    __syncthreads();
    int row = t >> 2, part = t & 3;
    int i = blockIdx.x * 32 + row;
    const float4* r1 = (const float4*)(H + ((size_t)t1 * NTT + i) * 128 + part * 32);
    const float4* r2 = (const float4*)(H + ((size_t)t2 * NTT + i) * 128 + part * 32);
    float s1 = 0.f, s2 = 0.f;
#pragma unroll
    for (int q = 0; q < 8; q++) {
        float4 a = r1[q], b = r2[q];
        int kb = part * 32 + q * 4;
        s1 += a.x * vs[kb] + a.y * vs[kb + 1] + a.z * vs[kb + 2] + a.w * vs[kb + 3];
        s2 += b.x * vd[kb] + b.y * vd[kb + 1] + b.z * vd[kb + 2] + b.w * vd[kb + 3];
    }
    s1 += __shfl_xor(s1, 1, 64); s1 += __shfl_xor(s1, 2, 64);
    s2 += __shfl_xor(s2, 1, 64); s2 += __shfl_xor(s2, 2, 64);
    if (part == 0) {
        esrc[p * NTT + i] = s1;
        edst[p * NTT + i] = s2;
    }
}
// sparse masked-softmax row aggregation; adj dtype per flag; bf16 output
__global__ __launch_bounds__(128) void gc1_attn_k(const void* __restrict__ adjv,
                                                  const float* __restrict__ H,
                                                  const float* __restrict__ esrc,
                                                  const float* __restrict__ edst,
                                                  u16* __restrict__ msgs,
                                                  const int* flagp) {
    int i = blockIdx.x, p = blockIdx.y, t = threadIdx.x;
    int t2 = p % 6;
    const bool f32 = flagp[0] != 0;
    size_t rowoff = ((size_t)p * NTT + i) * NTT;
    const float* edp = edst + p * NTT;
    float es = esrc[p * NTT + i];
    __shared__ int nzj[2048];
    __shared__ float nzs[2048];
    __shared__ int cnt;
    __shared__ float red[2];
    if (t == 0) cnt = 0;
    __syncthreads();
    int j0 = t * 16;
    float av[16];
    if (f32) {
        const float4* af = (const float4*)((const float*)adjv + rowoff + j0);
#pragma unroll
        for (int q = 0; q < 4; q++) {
            float4 d = af[q];
            av[q * 4 + 0] = d.x; av[q * 4 + 1] = d.y;
            av[q * 4 + 2] = d.z; av[q * 4 + 3] = d.w;
        }
    } else {
        const u16* ab = (const u16*)adjv + rowoff + j0;
        union { uint4 v; u16 u[8]; } a0, a1;
        a0.v = *(const uint4*)(ab);
        a1.v = *(const uint4*)(ab + 8);
#pragma unroll
        for (int q = 0; q < 16; q++) av[q] = b2f(q < 8 ? a0.u[q] : a1.u[q - 8]);
    }
    float lmax = -3e38f;
#pragma unroll
    for (int jj = 0; jj < 16; jj++) {
        if (av[jj] > 0.f) {
            int j = j0 + jj;
            float e = es + edp[j];
            float sv = e > 0.f ? e : 0.1f * e;   // leaky_relu, GAMMA=0.1
            lmax = fmaxf(lmax, sv);
            int kk = atomicAdd(&cnt, 1);
            nzj[kk] = j;
            nzs[kk] = sv;
        }
    }
    float mx = bmax128(lmax, red);
    int nnz = cnt;
    float psum = 0.f;
    for (int k = t; k < nnz; k += 128) {
        float w = expf(nzs[k] - mx);
        nzs[k] = w;
        psum += w;
    }
    float Z = bsum128(psum, red);
    const float* Ht = H + (size_t)t2 * NTT * 128;
    float acc = 0.f;
    if (nnz > 0) {
        for (int k = 0; k < nnz; k++) acc += nzs[k] * Ht[(size_t)nzj[k] * 128 + t];
        acc /= Z;
    } else {   // all-masked row -> uniform softmax over -1e9 scores
        for (int j = 0; j < NTT; j++) acc += Ht[(size_t)j * 128 + t];
        acc *= (1.f / 2048.f);
    }
    msgs[((size_t)p * NTT + i) * 128 + t] = f2b(acc);
}
// at1 lite: u = msgs@taW+tab precomputed by gemm_bat_k into ubuf (bf16).
__global__ __launch_bounds__(128) void at1_lite_k(const u16* __restrict__ msgs,
                                                  const u16* __restrict__ ubuf,
                                                  const u16* __restrict__ taq,
                                                  u16* __restrict__ X1) {
    int n = blockIdx.x, t1 = blockIdx.y, c = threadIdx.x;
    __shared__ float sv[6], red[2];
    float qcv = b2f(taq[t1 * 128 + c]);
    for (int t2 = 0; t2 < 6; t2++) {
        float u = b2f(ubuf[(((size_t)t1 * 6 + t2) * NTT + n) * 128 + c]);
        float s = bsum128(tanhf(u) * qcv, red);
        if (c == 0) sv[t2] = s;
    }
    __syncthreads();
    float mx = -3e38f;
    for (int t2 = 0; t2 < 6; t2++) mx = fmaxf(mx, sv[t2]);
    float z = 0.f;
    for (int t2 = 0; t2 < 6; t2++) z += expf(sv[t2] - mx);
    float o = 0.f;
    for (int t2 = 0; t2 < 6; t2++)
        o += expf(sv[t2] - mx) * b2f(msgs[(((size_t)t1 * 6 + t2) * NTT + n) * 128 + c]);
    o /= z;
    X1[((size_t)t1 * NTT + n) * 128 + c] = f2b(fmaxf(o, 0.f));
}
// dense hop-2 aggregation: adj dtype per flag
__global__ __launch_bounds__(128) void gc2_agg_k(const void* __restrict__ adjv,
                                                 size_t adjBase,
                                                 const float* __restrict__ hx,
                                                 const u16* __restrict__ bias,
                                                 float* __restrict__ msgs5,
                                                 const int* flagp) {
    int i = blockIdx.x, s = blockIdx.y, t = threadIdx.x;
    const bool f32 = flagp[0] != 0;
    size_t rowoff = adjBase + ((size_t)s * NTT + i) * NTT;
    __shared__ int nzj[2048];
    __shared__ float nzw[2048];
    __shared__ int cnt;
    if (t == 0) cnt = 0;
    __syncthreads();
    int j0 = t * 16;
    float av[16];
    if (f32) {
        const float4* af = (const float4*)((const float*)adjv + rowoff + j0);
#pragma unroll
        for (int q = 0; q < 4; q++) {
            float4 d = af[q];
            av[q * 4 + 0] = d.x; av[q * 4 + 1] = d.y;
            av[q * 4 + 2] = d.z; av[q * 4 + 3] = d.w;
        }
    } else {
        const u16* ab = (const u16*)adjv + rowoff + j0;
        union { uint4 v; u16 u[8]; } a0, a1;
        a0.v = *(const uint4*)(ab);
        a1.v = *(const uint4*)(ab + 8);
#pragma unroll
        for (int q = 0; q < 16; q++) av[q] = b2f(q < 8 ? a0.u[q] : a1.u[q - 8]);
    }
#pragma unroll
    for (int jj = 0; jj < 16; jj++) {
        if (av[jj] != 0.f) {
            int kk = atomicAdd(&cnt, 1);
            nzj[kk] = j0 + jj;
            nzw[kk] = av[jj];
        }
    }
    __syncthreads();
    const float* hxs = hx + (size_t)s * NTT * 128;
    float acc = 0.f;
    int nnz = cnt;
    for (int k = 0; k < nnz; k++) acc += nzw[k] * hxs[(size_t)nzj[k] * 128 + t];
    msgs5[((size_t)s * NTT + i) * 128 + t] = acc + b2f(bias[t]);
}
// at2 lite: u2 = msgs5 @ taW[11] + tab[11] precomputed by GEMM into ubuf2.
__global__ __launch_bounds__(128) void at2_head_lite_k(const float* __restrict__ msgs5,
                                                       const u16* __restrict__ ubuf2,
                                                       const u16* __restrict__ taq,
                                                       const u16* __restrict__ finW,
                                                       const u16* __restrict__ finb,
                                                       float* __restrict__ out) {
    int n = blockIdx.x, c = threadIdx.x;
    __shared__ float sv[6], red[2];
    float qcv = b2f(taq[11 * 128 + c]);
    for (int s = 0; s < 6; s++) {
        float u = b2f(ubuf2[((size_t)s * NTT + n) * 128 + c]);
        float sc = bsum128(tanhf(u) * qcv, red);
        if (c == 0) sv[s] = sc;
    }
    __syncthreads();
    float mx = -3e38f;
    for (int s = 0; s < 6; s++) mx = fmaxf(mx, sv[s]);
    float z = 0.f;
    for (int s = 0; s < 6; s++) z += expf(sv[s] - mx);
    float x2c = 0.f;
    for (int s = 0; s < 6; s++)
        x2c += expf(sv[s] - mx) * msgs5[((size_t)s * NTT + n) * 128 + c];
    x2c /= z;   // no relu in at2
    float l0 = bsum128(x2c * b2f(finW[c * 4 + 0]), red) + b2f(finb[0]);
    float l1 = bsum128(x2c * b2f(finW[c * 4 + 1]), red) + b2f(finb[1]);
    float l2 = bsum128(x2c * b2f(finW[c * 4 + 2]), red) + b2f(finb[2]);
    float l3 = bsum128(x2c * b2f(finW[c * 4 + 3]), red) + b2f(finb[3]);
    float m4 = fmaxf(fmaxf(l0, l1), fmaxf(l2, l3));
    float ls = logf(expf(l0 - m4) + expf(l1 - m4) + expf(l2 - m4) + expf(l3 - m4)) + m4;
    if (c < 4) {
        float v = (c == 0) ? l0 : (c == 1) ? l1 : (c == 2) ? l2 : l3;
        out[n * 4 + c] = v - ls;   // FLOAT32 output (reference dtype)
    }
}

// ---------------------------------------------------------------------------
extern "C" void kernel_launch(void* const* d_in, const int* in_sizes, int n_in,
                              void* d_out, int out_size, void* d_ws, size_t ws_size,
                              hipStream_t stream) {
    const void* x       = d_in[0];
    const int* ei       = (const int*)d_in[1];
    const int* batch    = (const int*)d_in[2];
    const int* rootidx  = (const int*)d_in[3];
    const int* type_x0  = (const int*)d_in[4];
    const int* type_x1  = (const int*)d_in[5];
    const int* type_x2  = (const int*)d_in[6];
    const int* root1    = (const int*)d_in[7];
    const int* parent1  = (const int*)d_in[8];
    const int* root2    = (const int*)d_in[9];
    const int* parent2  = (const int*)d_in[10];
    const int* type_x3  = (const int*)d_in[11];
    const int* root3    = (const int*)d_in[12];
    const int* type_x4  = (const int*)d_in[13];
    const int* root4    = (const int*)d_in[14];
    const void* adj     = d_in[15];

    char* ws = (char*)d_ws;
    int*   flag = (int*)(ws);
    u16*   pb   = (u16*)  (ws + 64 * 1024);   // bf16 params (1.31 MB)
    float* dinv = (float*)(ws + 2 * MiB);
    u16*   xwb  = (u16*)  (ws + 3 * MiB);     // [N,128] bf16 -> [3, 51.83)
    float* h2   = (float*)(ws + 52 * MiB);    // [N,128] f32 -> [52, 149.66)
    u16*   h1r  = (u16*)  (ws + 52 * MiB);    // ALIASES h2 start (dead first)
    // CSR scratch @150+ (Phase G only)
    int*   cnt_i   = (int*)(ws + 150 * MiB);
    int*   rowptr  = (int*)(ws + 151 * MiB);
    int*   cursor  = (int*)(ws + 152 * MiB);
    int*   csr_src = (int*)(ws + 153 * MiB);
    int*   bsum    = (int*)(ws + 158 * MiB);
    int*   bofs    = (int*)(ws + 158 * MiB + 4096);
    // Phase M aliases
    u16*   seqb = (u16*)  (ws + 3 * MiB);
    u16*   qb   = (u16*)  (ws + 18 * MiB);
    u16*   kb   = (u16*)  (ws + 33 * MiB);
    u16*   vb   = (u16*)  (ws + 150 * MiB);
    u16*   aob  = (u16*)  (ws + 165 * MiB);
    u16*   seqo = (u16*)  (ws + 18 * MiB);    // alias qb
    u16*   kpre = (u16*)  (ws + 33 * MiB);    // alias kb
    u16*   x0b  = (u16*)  (ws + 180 * MiB);   // [180,183)
    u16*   X1b  = (u16*)  (ws + 183 * MiB);   // [183,186)
    // Phase A aliases (h2 dead)
    float* Hb   = (float*)(ws + 52 * MiB);    // [52,58)
    float* esrc = (float*)(ws + 58 * MiB);
    float* edst = (float*)(ws + 59 * MiB);
    u16*   msgs = (u16*)  (ws + 60 * MiB);    // [60,78) bf16
    u16*   ubuf = (u16*)  (ws + 78 * MiB);    // [78,96) bf16
    float* hx   = (float*)(ws + 96 * MiB);    // [96,102)
    float* msg5 = (float*)(ws + 102 * MiB);   // [102,108)
    u16*   ubuf2= (u16*)  (ws + 60 * MiB);    // over dead msgs (3 MB)
    // transposed weights (all phases)
    u16*   pbT  = (u16*)  (ws + 186 * MiB);   // [186, 187.2)

    // ------- dtype probe + param normalization -------
    probe_k<<<1, 256, 0, stream>>>(x, flag);
    CTab tb;
    int kk = 0;
    auto add = [&](int i, unsigned off, unsigned n) {
        tb.e[kk].src = d_in[i]; tb.e[kk].dstOff = off; tb.e[kk].cnt = n; kk++;
    };
    add(16, O_W1, 32768);   add(17, O_b1, 128);     add(18, O_W2, 32768);
    add(19, O_b2, 128);     add(20, O_mhaW, 131072);add(21, O_mhab, 1024);
    add(22, O_attWq, 65536);add(23, O_attWk, 65536);add(24, O_attv, 512);
    add(25, O_fuseW, 1024); add(26, O_fuseb, 4);    add(27, O_gatW, 98304);
    add(28, O_asrc, 4608);  add(29, O_adst, 4608);  add(30, O_taW, 196608);
    add(31, O_tab, 1536);   add(32, O_taq, 1536);   add(33, O_gc2W, 16384);
    add(34, O_gc2b, 128);   add(35, O_finW, 512);   add(36, O_finb, 4);
    TTab tt;
    int tk = 0;
    auto addt = [&](int i, unsigned off, unsigned n, int msh, int ksh) {
        tt.e[tk].src = d_in[i]; tt.e[tk].dstOff = off; tt.e[tk].cnt = n;
        tt.e[tk].msh = msh; tt.e[tk].ksh = ksh; tk++;
    };
    addt(16, T_W1, 32768, 15, 8);     // K=256
    addt(18, T_W2, 32768, 15, 8);     // K=256
    addt(20, T_mhaW, 131072, 14, 7);  // K=128 x8
    addt(23, T_attWk, 65536, 14, 7);  // K=128 x4
    addt(27, T_gatW, 98304, 14, 7);   // K=128 x6
    addt(30, T_taW, 196608, 14, 7);   // K=128 x12
    addt(33, T_gc2W, 16384, 14, 7);   // K=128
    convp_k<<<256, 256, 0, stream>>>(tb, tt, pb, pbT, flag);

    // ---------------- Phase G: CSR build + two GCN layers ----------------
    const int NB = (NNODE + 1023) / 1024;
    hipMemsetAsync(cnt_i, 0, (size_t)NNODE * 4, stream);
    hist_k<<<(NEDGE + 255) / 256, 256, 0, stream>>>(ei, cnt_i);
    scan1_k<<<NB, 256, 0, stream>>>(cnt_i, bsum);
    scan2_k<<<1, 64, 0, stream>>>(bsum, bofs, NB, rowptr + NNODE);
    scan3_k<<<NB, 256, 0, stream>>>(cnt_i, bofs, rowptr, cursor, dinv);
    fill_k<<<(NEDGE + 255) / 256, 256, 0, stream>>>(ei, cursor, csr_src);

    gemm_bf16<256, true><<<(NNODE + 127) / 128, 256, 0, stream>>>(x, pbT + T_W1, (const u16*)nullptr, xwb, NNODE, flag);
    gather_gcn_k<true><<<(NNODE + 3) / 4, 256, 0, stream>>>(xwb, rowptr, csr_src, dinv, pb + O_b1, h1r);

    gemm_conv2<<<(NNODE + 127) / 128, 256, 0, stream>>>(h1r, batch, rootidx, pbT + T_W2, xwb, NNODE);
    gather_gcn_k<false><<<(NNODE + 3) / 4, 256, 0, stream>>>(xwb, rowptr, csr_src, dinv, pb + O_b2, h2);

    // ---------------- Phase M: build x0[0..5] ----------------
    x0copy_k<<<(NTT * 128) / 256, 256, 0, stream>>>(h2, type_x0, x0b);
    addatt12_k<<<NTT, 128, 0, stream>>>(h2, type_x1, root1, parent1,
                                        pb + O_attWq, pb + O_attWk, pb + O_attv,
                                        pb + O_fuseW, pb + O_fuseb, 0,
                                        x0b + 1 * NTT * 128);
    addatt12_k<<<NTT, 128, 0, stream>>>(h2, type_x2, root2, parent2,
                                        pb + O_attWq + 16384, pb + O_attWk + 16384,
                                        pb + O_attv + 128, pb + O_fuseW + 256,
                                        pb + O_fuseb, 1,
                                        x0b + 2 * NTT * 128);
    for (int i = 0; i < 2; i++) {
        int L = i ? 30 : 13;
        const int* tx = i ? type_x4 : type_x3;
        const int* rt = i ? root4 : root3;
        int M = NTT * L;
        gather_seq_k<<<(M * 128 + 255) / 256, 256, 0, stream>>>(h2, tx, seqb, M * 128);
        gemm_bf16<128, true><<<(M + 127) / 128, 256, 0, stream>>>(seqb, pbT + T_mhaW + (i * 4 + 0) * 16384,
                                                                  pb + O_mhab + (i * 4 + 0) * 128, qb, M, nullptr);
        gemm_bf16<128, true><<<(M + 127) / 128, 256, 0, stream>>>(seqb, pbT + T_mhaW + (i * 4 + 1) * 16384,
                                                                  pb + O_mhab + (i * 4 + 1) * 128, kb, M, nullptr);
        gemm_bf16<128, true><<<(M + 127) / 128, 256, 0, stream>>>(seqb, pbT + T_mhaW + (i * 4 + 2) * 16384,
                                                                  pb + O_mhab + (i * 4 + 2) * 128, vb, M, nullptr);
        mha_attn_k<<<dim3(NTT, 8), 64, 0, stream>>>(qb, kb, vb, aob, L);
        gemm_bf16<128, true><<<(M + 127) / 128, 256, 0, stream>>>(aob, pbT + T_mhaW + (i * 4 + 3) * 16384,
                                                                  pb + O_mhab + (i * 4 + 3) * 128, seqo, M, nullptr);
        gemm_bf16<128, true><<<(M + 127) / 128, 256, 0, stream>>>(seqo, pbT + T_attWk + (2 + i) * 16384,
                                                                  (const u16*)nullptr, kpre, M, nullptr);
        addatt_root_k<<<NTT, 128, 0, stream>>>(seqo, kpre, h2, rt,
                                               pb + O_attWq + (2 + i) * 16384,
                                               pb + O_attv + (2 + i) * 128,
                                               pb + O_fuseW + (2 + i) * 256,
                                               pb + O_fuseb, 2 + i, L,
                                               x0b + (3 + i) * NTT * 128);
    }

    // ---------------- Phase A: hetero GAT + heads ----------------
    gemm_bat_k<128, false><<<dim3(NTT / 128, 6), 256, 0, stream>>>(
        x0b, (size_t)NTT * 128, pbT + T_gatW, 16384, (const u16*)nullptr, 0,
        Hb, (size_t)NTT * 128, NTT);
    gat_e2_k<<<dim3(NTT / 32, 36), 128, 0, stream>>>(Hb, pb + O_asrc, pb + O_adst, esrc, edst);
    gc1_attn_k<<<dim3(NTT, 36), 128, 0, stream>>>(adj, Hb, esrc, edst, msgs, flag);
    gemm_bat_k<128, true><<<dim3((6 * NTT) / 128, 6), 256, 0, stream>>>(
        msgs, (size_t)6 * NTT * 128, pbT + T_taW, 16384, pb + O_tab, 128,
        ubuf, (size_t)6 * NTT * 128, 6 * NTT);
    at1_lite_k<<<dim3(NTT, 6), 128, 0, stream>>>(msgs, ubuf, pb + O_taq, X1b);
    gemm_bf16<128, false><<<(6 * NTT) / 128, 256, 0, stream>>>(X1b, pbT + T_gc2W, (const u16*)nullptr, hx, 6 * NTT, nullptr);
    gc2_agg_k<<<dim3(NTT, 6), 128, 0, stream>>>(adj, (size_t)5 * 6 * NTT * NTT, hx,
                                                pb + O_gc2b, msg5, flag);
    // at2: u2 = msgs5 @ taW[11] + tab[11] via MFMA (forced f32-A path)
    gemm_bf16<128, true><<<(6 * NTT) / 128, 256, 0, stream>>>(msg5, pbT + T_taW + 11 * 16384,
                                                              pb + O_tab + 11 * 128, ubuf2, 6 * NTT, flag + 1);
    at2_head_lite_k<<<NTT, 128, 0, stream>>>(msg5, ubuf2, pb + O_taq,
                                             pb + O_finW, pb + O_finb, (float*)d_out);
}